// Round 9
// baseline (640.669 us; speedup 1.0000x reference)
//
#include <hip/hip_runtime.h>
#include <math.h>

#define N_NODES 50000
#define N_EDGES 600000
#define F_INPUT 128
#define HCDIM 256
#define NGRAPH 64
#define NCLS 3
#define MPAD 50048   // 391 * 128, GEMM M padded
#define SCAN_NB ((N_NODES + 255) / 256)   // 196
#define LOG2E 1.4426950408889634f

// fused prep kernel block ranges
#define SPLITX_NB (MPAD * F_INPUT / 4 / 256)            // 6256
#define ZERO_NB   (((MPAD - N_NODES) * HCDIM / 4 + 255) / 256)  // 12
#define WPREP_NB  (512 * (F_INPUT + HCDIM + HCDIM) / 256)       // 1280
#define PREP_NB   (SPLITX_NB + ZERO_NB + WPREP_NB)
// fused hist+boundary ranges
#define HIST_NB   ((N_EDGES + N_NODES + 255) / 256)     // 2540
#define BND_NB    ((N_NODES + 255) / 256)               // 196

typedef float f32x4 __attribute__((ext_vector_type(4)));
typedef float f32x2 __attribute__((ext_vector_type(2)));
typedef _Float16 f16x8 __attribute__((ext_vector_type(8)));
typedef _Float16 f16x4 __attribute__((ext_vector_type(4)));
typedef _Float16 h2 __attribute__((ext_vector_type(2)));

__device__ __forceinline__ void gl_lds16(const void* g, void* l) {
    __builtin_amdgcn_global_load_lds(
        (const __attribute__((address_space(1))) unsigned int*)g,
        (__attribute__((address_space(3))) unsigned int*)l, 16, 0, 0);
}

__device__ __forceinline__ h2 bch2(unsigned int u) { return __builtin_bit_cast(h2, u); }
__device__ __forceinline__ h2 pk16(float a, float b) {
    return __builtin_bit_cast(h2, __builtin_amdgcn_cvt_pkrtz(a, b));
}

// packed leaky_relu(0.2): max(v,0) + 0.2*min(v,0)
__device__ __forceinline__ h2 lrelu2(h2 v) {
    const h2 z = {(_Float16)0.f, (_Float16)0.f};
    const h2 c = {(_Float16)0.2f, (_Float16)0.2f};
    h2 mx = __builtin_elementwise_max(v, z);
    h2 mn = __builtin_elementwise_min(v, z);
    return mx + mn * c;
}

// ============================ hist + boundary (fused) ============================
__global__ void hist_boundary_kernel(const int* __restrict__ ei, int* __restrict__ deg,
                                     const int* __restrict__ batch,
                                     int* __restrict__ startg, int* __restrict__ endg) {
    int b = blockIdx.x;
    if (b < HIST_NB) {
        int i = b * 256 + threadIdx.x;
        int total = N_EDGES + N_NODES;
        if (i >= total) return;
        int d = (i < N_EDGES) ? ei[N_EDGES + i] : (i - N_EDGES);
        atomicAdd(&deg[d], 1);
    } else {
        int i = (b - HIST_NB) * 256 + threadIdx.x;
        if (i >= N_NODES) return;
        int g = batch[i];
        if (i == 0 || batch[i - 1] != g) startg[g] = i;
        if (i == N_NODES - 1 || batch[i + 1] != g) endg[g] = i + 1;
    }
}

// ============================ CSR scan ============================
__global__ void block_scan_kernel(const int* __restrict__ deg, int* __restrict__ rowptr,
                                  int* __restrict__ bsums) {
    __shared__ int wt[4];
    int b = blockIdx.x, t = threadIdx.x, lane = t & 63, wid = t >> 6;
    int i = b * 256 + t;
    int v = (i < N_NODES) ? deg[i] : 0;
    int x = v;
    #pragma unroll
    for (int off = 1; off < 64; off <<= 1) {
        int y = __shfl_up(x, off, 64);
        if (lane >= off) x += y;
    }
    if (lane == 63) wt[wid] = x;
    __syncthreads();
    if (t == 0) {
        int s = 0;
        #pragma unroll
        for (int j = 0; j < 4; ++j) { int tv = wt[j]; wt[j] = s; s += tv; }
        bsums[b] = s;
    }
    __syncthreads();
    if (i < N_NODES) rowptr[i] = wt[wid] + x - v;
}

__global__ void scan_bsums_kernel(int* __restrict__ bsums) {
    __shared__ int wt[4];
    int t = threadIdx.x, lane = t & 63, wid = t >> 6;
    int v = (t < SCAN_NB) ? bsums[t] : 0;
    int x = v;
    #pragma unroll
    for (int off = 1; off < 64; off <<= 1) {
        int y = __shfl_up(x, off, 64);
        if (lane >= off) x += y;
    }
    if (lane == 63) wt[wid] = x;
    __syncthreads();
    if (t == 0) {
        int s = 0;
        #pragma unroll
        for (int j = 0; j < 4; ++j) { int tv = wt[j]; wt[j] = s; s += tv; }
    }
    __syncthreads();
    if (t < SCAN_NB) bsums[t] = wt[wid] + x - v;
}

__global__ void add_off_kernel(int* __restrict__ rowptr, int* __restrict__ cursor,
                               const int* __restrict__ bsums) {
    int i = blockIdx.x * 256 + threadIdx.x;
    if (i < N_NODES) {
        int r = rowptr[i] + bsums[blockIdx.x];
        rowptr[i] = r;
        cursor[i] = r;
    }
    if (i == 0) rowptr[N_NODES] = N_EDGES + N_NODES;
}

// colx stores BYTE offsets into the fp8 xl matrix: s * HCDIM (256 B rows)
__global__ void fill_kernel(const int* __restrict__ ei, int* __restrict__ cursor,
                            int* __restrict__ colx) {
    int i = blockIdx.x * 256 + threadIdx.x;
    int total = N_EDGES + N_NODES;
    if (i >= total) return;
    int s, d;
    if (i < N_EDGES) { s = ei[i]; d = ei[N_EDGES + i]; }
    else             { s = i - N_EDGES; d = s; }
    int pos = atomicAdd(&cursor[d], 1);
    colx[pos] = s * HCDIM;
}

// ============================ Fused prep: x->fp16, pad zero, W->fp16 n-major ============================
__global__ void prep_kernel(const float* __restrict__ x, _Float16* __restrict__ A,
                            _Float16* __restrict__ Bt0, _Float16* __restrict__ Bt1,
                            _Float16* __restrict__ Bt2,
                            const float* __restrict__ Wl0, const float* __restrict__ Wr0,
                            const float* __restrict__ Wl1, const float* __restrict__ Wr1,
                            const float* __restrict__ Wl2, const float* __restrict__ Wr2) {
    int b = blockIdx.x;
    if (b < SPLITX_NB) {
        int base = (b * 256 + threadIdx.x) * 4;
        int row = base >> 7;
        float4 v = make_float4(0.f, 0.f, 0.f, 0.f);
        if (row < N_NODES) v = *(const float4*)&x[base];
        f16x4 o;
        o.x = (_Float16)v.x; o.y = (_Float16)v.y; o.z = (_Float16)v.z; o.w = (_Float16)v.w;
        *(f16x4*)&A[base] = o;
    } else if (b < SPLITX_NB + ZERO_NB) {
        int i = ((b - SPLITX_NB) * 256 + threadIdx.x) * 4;
        if (i < (MPAD - N_NODES) * HCDIM) {
            f16x4 z = {(_Float16)0.f, (_Float16)0.f, (_Float16)0.f, (_Float16)0.f};
            *(f16x4*)&A[(size_t)N_NODES * HCDIM + i] = z;
        }
    } else {
        int t = (b - SPLITX_NB - ZERO_NB) * 256 + threadIdx.x;
        const float* Wl; const float* Wr; _Float16* Bt; int K;
        if (t < 512 * F_INPUT)            { Wl = Wl0; Wr = Wr0; Bt = Bt0; K = F_INPUT; }
        else if (t < 512 * (F_INPUT + HCDIM)) { t -= 512 * F_INPUT; Wl = Wl1; Wr = Wr1; Bt = Bt1; K = HCDIM; }
        else                              { t -= 512 * (F_INPUT + HCDIM); Wl = Wl2; Wr = Wr2; Bt = Bt2; K = HCDIM; }
        int n = t & 511, k = t >> 9;
        float w = (n < 256) ? Wl[k * 256 + n] : Wr[k * 256 + (n - 256)];
        Bt[n * K + k] = (_Float16)w;
    }
}

// ============================ fp16 MFMA GEMM, BK=64 ============================
// C[MPAD,512] = A[MPAD,K] @ B[K,512]; 128x128 tile, BK=64 (half the barrier drains of BK=32).
// XOR bank swizzle: global k-chunk pg = pl ^ (r&7); fragment reads hit all 32 banks at 2-way (free).
// xl output encoded fp8 e4m3.
__global__ __launch_bounds__(256) void gemm_mfma(
    const _Float16* __restrict__ A, const _Float16* __restrict__ B,
    int K,
    const float* __restrict__ bl, const float* __restrict__ br,
    unsigned char* __restrict__ xl8, _Float16* __restrict__ xrh)
{
    __shared__ _Float16 sA[128 * 64], sB[128 * 64];
    int tid = threadIdx.x;
    int lane = tid & 63, wave = tid >> 6;
    int wm = wave >> 1, wn = wave & 1;
    int bx = blockIdx.x >> 2, by = blockIdx.x & 3;
    int row0 = bx * 128;
    int n0 = by * 128;
    int quad = lane >> 4, l16 = lane & 15;

    f32x4 acc[4][4];
    #pragma unroll
    for (int i = 0; i < 4; ++i)
        #pragma unroll
        for (int j = 0; j < 4; ++j)
            acc[i][j] = (f32x4){0.f, 0.f, 0.f, 0.f};

    for (int k0 = 0; k0 < K; k0 += 64) {
        __syncthreads();
        #pragma unroll
        for (int pass = 0; pass < 4; ++pass) {
            int c = tid + pass * 256;           // chunk 0..1023 (16 B each)
            int r = c >> 3;                     // tile row
            int pl = c & 7;                     // physical k-chunk in LDS row
            int pg = pl ^ (r & 7);              // global k-chunk (swizzled)
            size_t ga = (size_t)(row0 + r) * K + k0 + pg * 8;
            size_t gb = (size_t)(n0 + r) * K + k0 + pg * 8;
            gl_lds16(A + ga, sA + c * 8);
            gl_lds16(B + gb, sB + c * 8);
        }
        __syncthreads();

        #pragma unroll
        for (int kk = 0; kk < 2; ++kk) {
            f16x8 fa[4], fb[4];
            #pragma unroll
            for (int i = 0; i < 4; ++i) {
                int rr = wm * 64 + i * 16 + l16;
                int ca = (kk * 4 + quad) ^ (rr & 7);
                fa[i] = *(const f16x8*)&sA[rr * 64 + ca * 8];
                int nn = wn * 64 + i * 16 + l16;
                int cb = (kk * 4 + quad) ^ (nn & 7);
                fb[i] = *(const f16x8*)&sB[nn * 64 + cb * 8];
            }
            #pragma unroll
            for (int i = 0; i < 4; ++i)
                #pragma unroll
                for (int j = 0; j < 4; ++j)
                    acc[i][j] = __builtin_amdgcn_mfma_f32_16x16x32_f16(fa[i], fb[j], acc[i][j], 0, 0, 0);
        }
    }

    if (by < 2) {
        int cb0 = by * 128;
        #pragma unroll
        for (int j = 0; j < 4; ++j) {
            int col = cb0 + wn * 64 + j * 16 + l16;
            float bj = bl[col];
            #pragma unroll
            for (int i = 0; i < 4; ++i) {
                int rbase = row0 + wm * 64 + i * 16 + quad * 4;
                #pragma unroll
                for (int r = 0; r < 4; ++r) {
                    int row = rbase + r;
                    if (row < N_NODES) {
                        float v = acc[i][j][r] + bj;
                        int pk = __builtin_amdgcn_cvt_pk_fp8_f32(v, v, 0, false);
                        xl8[(size_t)row * HCDIM + col] = (unsigned char)pk;
                    }
                }
            }
        }
    } else {
        int cb0 = (by - 2) * 128;
        #pragma unroll
        for (int j = 0; j < 4; ++j) {
            int col = cb0 + wn * 64 + j * 16 + l16;
            float bj = br[col];
            #pragma unroll
            for (int i = 0; i < 4; ++i) {
                int rbase = row0 + wm * 64 + i * 16 + quad * 4;
                #pragma unroll
                for (int r = 0; r < 4; ++r) {
                    int row = rbase + r;
                    if (row < N_NODES)
                        xrh[(size_t)row * HCDIM + col] = (_Float16)(acc[i][j][r] + bj);
                }
            }
        }
    }
}

// ============================ Edge phase: fp8 gather, 2-edge batched online softmax ============================
// One wave per dst node; lane l: head l>>4, channels (l&15)*4..+3 (4 fp8 bytes = 1 dword/edge/lane).
// colx holds byte offsets (s*256). mode 0: fp16 h out (pool). mode 1: relu'd fp16 (next GEMM's A).
__global__ __launch_bounds__(256) void gat_edge(
    const unsigned char* __restrict__ xl8, const _Float16* __restrict__ xrh,
    const float* __restrict__ att, const float* __restrict__ bias,
    const int* __restrict__ rowptr, const int* __restrict__ colx,
    _Float16* __restrict__ outh, _Float16* __restrict__ onext, int mode)
{
    int wave = threadIdx.x >> 6;
    int lane = threadIdx.x & 63;
    int node = blockIdx.x * 4 + wave;
    if (node >= N_NODES) return;
    int lb8  = lane * 4;                     // byte offset within fp8 row
    int lb16 = lane * 8;                     // byte offset within fp16 row
    const char* xlb = (const char*)xl8;

    uint2 xrr = *(const uint2*)((const char*)xrh + (size_t)node * (HCDIM * 2) + lb16);
    h2 xra = bch2(xrr.x), xrb = bch2(xrr.y);
    float4 at4 = *(const float4*)&att[lane * 4];
    h2 ata = {(_Float16)at4.x, (_Float16)at4.y};
    h2 atb = {(_Float16)at4.z, (_Float16)at4.w};

    int e0 = rowptr[node], e1 = rowptr[node + 1];
    float m = -INFINITY, denom = 0.f;
    float4 acc = make_float4(0.f, 0.f, 0.f, 0.f);

    unsigned int o0 = (unsigned)colx[e0];
    unsigned int o1 = (unsigned)colx[(e0 + 1 < e1) ? e0 + 1 : e0];
    unsigned int d0 = *(const unsigned int*)(xlb + (size_t)o0 + lb8);
    unsigned int d1 = *(const unsigned int*)(xlb + (size_t)o1 + lb8);

    for (int e = e0; e < e1; e += 2) {
        bool v1 = (e + 1 < e1);
        int i2 = (e + 2 < e1) ? e + 2 : e1 - 1;
        int i3 = (e + 3 < e1) ? e + 3 : e1 - 1;
        unsigned int on0 = (unsigned)colx[i2], on1 = (unsigned)colx[i3];
        unsigned int nd0 = *(const unsigned int*)(xlb + (size_t)on0 + lb8);
        unsigned int nd1 = *(const unsigned int*)(xlb + (size_t)on1 + lb8);

        f32x2 lo0 = __builtin_amdgcn_cvt_pk_f32_fp8(d0, false);
        f32x2 hi0 = __builtin_amdgcn_cvt_pk_f32_fp8(d0, true);
        f32x2 lo1 = __builtin_amdgcn_cvt_pk_f32_fp8(d1, false);
        f32x2 hi1 = __builtin_amdgcn_cvt_pk_f32_fp8(d1, true);
        h2 a0 = pk16(lo0.x, lo0.y);
        h2 b0 = pk16(hi0.x, hi0.y);
        h2 a1 = pk16(lo1.x, lo1.y);
        h2 b1 = pk16(hi1.x, hi1.y);

        h2 l0a = lrelu2(a0 + xra), l0b = lrelu2(b0 + xrb);
        h2 l1a = lrelu2(a1 + xra), l1b = lrelu2(b1 + xrb);
        float p0 = __builtin_amdgcn_fdot2(l0a, ata, 0.f, false);
        p0 = __builtin_amdgcn_fdot2(l0b, atb, p0, false);
        float p1 = __builtin_amdgcn_fdot2(l1a, ata, 0.f, false);
        p1 = __builtin_amdgcn_fdot2(l1b, atb, p1, false);

        p0 += __shfl_xor(p0, 1, 64);  p1 += __shfl_xor(p1, 1, 64);
        p0 += __shfl_xor(p0, 2, 64);  p1 += __shfl_xor(p1, 2, 64);
        p0 += __shfl_xor(p0, 4, 64);  p1 += __shfl_xor(p1, 4, 64);
        p0 += __shfl_xor(p0, 8, 64);  p1 += __shfl_xor(p1, 8, 64);
        p0 *= LOG2E;
        p1 = v1 ? p1 * LOG2E : -INFINITY;

        float mn = fmaxf(fmaxf(m, p0), p1);
        float corr = exp2f(m - mn);
        float w0 = exp2f(p0 - mn);
        float w1 = exp2f(p1 - mn);
        denom = denom * corr + w0 + w1;
        acc.x = acc.x * corr + w0 * lo0.x + w1 * lo1.x;
        acc.y = acc.y * corr + w0 * lo0.y + w1 * lo1.y;
        acc.z = acc.z * corr + w0 * hi0.x + w1 * hi1.x;
        acc.w = acc.w * corr + w0 * hi0.y + w1 * hi1.y;
        m = mn;
        d0 = nd0; d1 = nd1;
    }

    float inv = 1.f / denom;
    float4 b4 = *(const float4*)&bias[lane * 4];
    float ox = acc.x * inv + b4.x;
    float oy = acc.y * inv + b4.y;
    float oz = acc.z * inv + b4.z;
    float ow = acc.w * inv + b4.w;
    if (mode == 0) {
        f16x4 h;
        h.x = (_Float16)ox; h.y = (_Float16)oy;
        h.z = (_Float16)oz; h.w = (_Float16)ow;
        *(f16x4*)((char*)outh + (size_t)node * (HCDIM * 2) + lb16) = h;
    } else {
        f16x4 h;
        h.x = (_Float16)fmaxf(ox, 0.f); h.y = (_Float16)fmaxf(oy, 0.f);
        h.z = (_Float16)fmaxf(oz, 0.f); h.w = (_Float16)fmaxf(ow, 0.f);
        *(f16x4*)((char*)onext + (size_t)node * (HCDIM * 2) + lb16) = h;
    }
}

// ============================ Pooling (fp16 input) ============================
__global__ __launch_bounds__(256) void pool_kernel(
    const _Float16* __restrict__ h, const int* __restrict__ startg,
    const int* __restrict__ endg, float* __restrict__ p)
{
    __shared__ float4 sS[4][64];
    __shared__ float4 sM[4][64];
    int g = blockIdx.x;
    int lane = threadIdx.x & 63;
    int sub = threadIdx.x >> 6;
    int c0 = lane * 4;
    int s = startg[g], e = endg[g];
    float4 sum = make_float4(0.f, 0.f, 0.f, 0.f);
    float4 mx = make_float4(-INFINITY, -INFINITY, -INFINITY, -INFINITY);
    for (int i = s + sub; i < e; i += 4) {
        uint2 u = *(const uint2*)&h[(size_t)i * HCDIM + c0];
        h2 a = bch2(u.x), b = bch2(u.y);
        float4 v = make_float4((float)a.x, (float)a.y, (float)b.x, (float)b.y);
        sum.x += v.x; sum.y += v.y; sum.z += v.z; sum.w += v.w;
        mx.x = fmaxf(mx.x, v.x); mx.y = fmaxf(mx.y, v.y);
        mx.z = fmaxf(mx.z, v.z); mx.w = fmaxf(mx.w, v.w);
    }
    sS[sub][lane] = sum; sM[sub][lane] = mx;
    __syncthreads();
    if (sub == 0) {
        #pragma unroll
        for (int j = 1; j < 4; ++j) {
            float4 a = sS[j][lane], b = sM[j][lane];
            sum.x += a.x; sum.y += a.y; sum.z += a.z; sum.w += a.w;
            mx.x = fmaxf(mx.x, b.x); mx.y = fmaxf(mx.y, b.y);
            mx.z = fmaxf(mx.z, b.z); mx.w = fmaxf(mx.w, b.w);
        }
        int cnt = e - s;
        float inv = 1.f / fmaxf((float)cnt, 1.f);
        float4 o;
        o.x = sum.x * inv + mx.x; o.y = sum.y * inv + mx.y;
        o.z = sum.z * inv + mx.z; o.w = sum.w * inv + mx.w;
        *(float4*)&p[(size_t)g * HCDIM + c0] = o;
    }
}

// ============================ Head: logits + softmax ============================
__global__ void logits_kernel(const float* __restrict__ p, const float* __restrict__ Wout,
                              const float* __restrict__ bout, float* __restrict__ out)
{
    __shared__ float red[256];
    __shared__ float lg[NCLS];
    int g = blockIdx.x, t = threadIdx.x;
    float pv = p[g * HCDIM + t];
    for (int j = 0; j < NCLS; ++j) {
        red[t] = pv * Wout[t * NCLS + j];
        __syncthreads();
        for (int off = 128; off > 0; off >>= 1) {
            if (t < off) red[t] += red[t + off];
            __syncthreads();
        }
        if (t == 0) lg[j] = red[0] + bout[j];
        __syncthreads();
    }
    if (t == 0) {
        float mx = fmaxf(lg[0], fmaxf(lg[1], lg[2]));
        float e0 = __expf(lg[0] - mx), e1 = __expf(lg[1] - mx), e2 = __expf(lg[2] - mx);
        float inv = 1.f / (e0 + e1 + e2);
        out[g * NCLS + 0] = e0 * inv;
        out[g * NCLS + 1] = e1 * inv;
        out[g * NCLS + 2] = e2 * inv;
    }
}

// ============================ Orchestration ============================
extern "C" void kernel_launch(void* const* d_in, const int* in_sizes, int n_in,
                              void* d_out, int out_size, void* d_ws, size_t ws_size,
                              hipStream_t stream) {
    const float* x     = (const float*)d_in[0];
    const int*   ei    = (const int*)d_in[1];
    const int*   batch = (const int*)d_in[2];
    const float *Wl[3], *bl[3], *Wr[3], *br[3], *att[3], *bias[3];
    for (int li = 0; li < 3; ++li) {
        int b = 3 + li * 6;
        Wl[li]   = (const float*)d_in[b + 0];
        bl[li]   = (const float*)d_in[b + 1];
        Wr[li]   = (const float*)d_in[b + 2];
        br[li]   = (const float*)d_in[b + 3];
        att[li]  = (const float*)d_in[b + 4];
        bias[li] = (const float*)d_in[b + 5];
    }
    const float* Wout = (const float*)d_in[21];
    const float* bout = (const float*)d_in[22];
    float* out = (float*)d_out;

    size_t off = 0;
    char* wsb = (char*)d_ws;
    auto alloc = [&](size_t bytes) -> char* {
        char* ptr = wsb + off;
        off += (bytes + 255) & ~(size_t)255;
        return ptr;
    };
    int* rowptr  = (int*)alloc((N_NODES + 1) * sizeof(int));
    int* deg     = (int*)alloc(N_NODES * sizeof(int));
    int* cursor  = (int*)alloc(N_NODES * sizeof(int));
    int* bsums   = (int*)alloc(256 * sizeof(int));
    int* colx    = (int*)alloc((size_t)(N_EDGES + N_NODES) * sizeof(int));
    int* startg  = (int*)alloc(NGRAPH * sizeof(int));
    int* endg    = (int*)alloc(NGRAPH * sizeof(int));
    _Float16* Abuf = (_Float16*)alloc((size_t)MPAD * HCDIM * sizeof(_Float16));
    _Float16* Bt[3];
    for (int li = 0; li < 3; ++li) {
        int K = (li == 0) ? F_INPUT : HCDIM;
        Bt[li] = (_Float16*)alloc((size_t)512 * K * sizeof(_Float16));
    }
    unsigned char* xl8 = (unsigned char*)alloc((size_t)N_NODES * HCDIM);
    _Float16* xrh  = (_Float16*)alloc((size_t)N_NODES * HCDIM * sizeof(_Float16));
    _Float16* hbuf = (_Float16*)alloc((size_t)N_NODES * HCDIM * sizeof(_Float16));
    float* pbuf    = (float*)alloc((size_t)NGRAPH * HCDIM * sizeof(float));

    hipMemsetAsync(deg, 0, N_NODES * sizeof(int), stream);
    hipMemsetAsync(startg, 0, NGRAPH * sizeof(int), stream);
    hipMemsetAsync(endg, 0, NGRAPH * sizeof(int), stream);

    hist_boundary_kernel<<<HIST_NB + BND_NB, 256, 0, stream>>>(ei, deg, batch, startg, endg);
    block_scan_kernel<<<SCAN_NB, 256, 0, stream>>>(deg, rowptr, bsums);
    scan_bsums_kernel<<<1, 256, 0, stream>>>(bsums);
    add_off_kernel<<<SCAN_NB, 256, 0, stream>>>(rowptr, cursor, bsums);
    fill_kernel<<<(N_EDGES + N_NODES + 255) / 256, 256, 0, stream>>>(ei, cursor, colx);

    prep_kernel<<<PREP_NB, 256, 0, stream>>>(x, Abuf, Bt[0], Bt[1], Bt[2],
                                             Wl[0], Wr[0], Wl[1], Wr[1], Wl[2], Wr[2]);

    for (int li = 0; li < 3; ++li) {
        int K = (li == 0) ? F_INPUT : HCDIM;
        gemm_mfma<<<(MPAD / 128) * 4, 256, 0, stream>>>(
            Abuf, Bt[li], K, bl[li], br[li], xl8, xrh);
        if (li < 2) {
            gat_edge<<<N_NODES / 4, 256, 0, stream>>>(
                xl8, xrh, att[li], bias[li], rowptr, colx, nullptr, Abuf, 1);
        } else {
            gat_edge<<<N_NODES / 4, 256, 0, stream>>>(
                xl8, xrh, att[li], bias[li], rowptr, colx, hbuf, nullptr, 0);
        }
    }

    pool_kernel<<<NGRAPH, 256, 0, stream>>>(hbuf, startg, endg, pbuf);
    logits_kernel<<<NGRAPH, 256, 0, stream>>>(pbuf, Wout, bout, out);
}

// Round 10
// 605.263 us; speedup vs baseline: 1.0585x; 1.0585x over previous
//
#include <hip/hip_runtime.h>
#include <math.h>

#define N_NODES 50000
#define N_EDGES 600000
#define F_INPUT 128
#define HCDIM 256
#define NGRAPH 64
#define NCLS 3
#define MPAD 50048   // 391 * 128, GEMM M padded
#define SCAN_NB ((N_NODES + 255) / 256)   // 196
#define LOG2E 1.4426950408889634f

// fused prep kernel block ranges
#define SPLITX_NB (MPAD * F_INPUT / 4 / 256)            // 6256
#define ZERO_NB   (((MPAD - N_NODES) * HCDIM / 4 + 255) / 256)  // 12
#define WPREP_NB  (512 * (F_INPUT + HCDIM + HCDIM) / 256)       // 1280
#define PREP_NB   (SPLITX_NB + ZERO_NB + WPREP_NB)
// fused hist+boundary ranges
#define HIST_NB   ((N_EDGES + N_NODES + 255) / 256)     // 2540
#define BND_NB    ((N_NODES + 255) / 256)               // 196

typedef float f32x4 __attribute__((ext_vector_type(4)));
typedef float f32x2 __attribute__((ext_vector_type(2)));
typedef _Float16 f16x8 __attribute__((ext_vector_type(8)));
typedef _Float16 f16x4 __attribute__((ext_vector_type(4)));
typedef _Float16 h2 __attribute__((ext_vector_type(2)));

__device__ __forceinline__ void gl_lds16(const void* g, void* l) {
    __builtin_amdgcn_global_load_lds(
        (const __attribute__((address_space(1))) unsigned int*)g,
        (__attribute__((address_space(3))) unsigned int*)l, 16, 0, 0);
}

__device__ __forceinline__ h2 bch2(unsigned int u) { return __builtin_bit_cast(h2, u); }
__device__ __forceinline__ h2 pk16(float a, float b) {
    return __builtin_bit_cast(h2, __builtin_amdgcn_cvt_pkrtz(a, b));
}

// packed leaky_relu(0.2): max(v,0) + 0.2*min(v,0)
__device__ __forceinline__ h2 lrelu2(h2 v) {
    const h2 z = {(_Float16)0.f, (_Float16)0.f};
    const h2 c = {(_Float16)0.2f, (_Float16)0.2f};
    h2 mx = __builtin_elementwise_max(v, z);
    h2 mn = __builtin_elementwise_min(v, z);
    return mx + mn * c;
}

// ============================ hist + boundary (fused) ============================
__global__ void hist_boundary_kernel(const int* __restrict__ ei, int* __restrict__ deg,
                                     const int* __restrict__ batch,
                                     int* __restrict__ startg, int* __restrict__ endg) {
    int b = blockIdx.x;
    if (b < HIST_NB) {
        int i = b * 256 + threadIdx.x;
        int total = N_EDGES + N_NODES;
        if (i >= total) return;
        int d = (i < N_EDGES) ? ei[N_EDGES + i] : (i - N_EDGES);
        atomicAdd(&deg[d], 1);
    } else {
        int i = (b - HIST_NB) * 256 + threadIdx.x;
        if (i >= N_NODES) return;
        int g = batch[i];
        if (i == 0 || batch[i - 1] != g) startg[g] = i;
        if (i == N_NODES - 1 || batch[i + 1] != g) endg[g] = i + 1;
    }
}

// ============================ CSR scan ============================
__global__ void block_scan_kernel(const int* __restrict__ deg, int* __restrict__ rowptr,
                                  int* __restrict__ bsums) {
    __shared__ int wt[4];
    int b = blockIdx.x, t = threadIdx.x, lane = t & 63, wid = t >> 6;
    int i = b * 256 + t;
    int v = (i < N_NODES) ? deg[i] : 0;
    int x = v;
    #pragma unroll
    for (int off = 1; off < 64; off <<= 1) {
        int y = __shfl_up(x, off, 64);
        if (lane >= off) x += y;
    }
    if (lane == 63) wt[wid] = x;
    __syncthreads();
    if (t == 0) {
        int s = 0;
        #pragma unroll
        for (int j = 0; j < 4; ++j) { int tv = wt[j]; wt[j] = s; s += tv; }
        bsums[b] = s;
    }
    __syncthreads();
    if (i < N_NODES) rowptr[i] = wt[wid] + x - v;
}

__global__ void scan_bsums_kernel(int* __restrict__ bsums) {
    __shared__ int wt[4];
    int t = threadIdx.x, lane = t & 63, wid = t >> 6;
    int v = (t < SCAN_NB) ? bsums[t] : 0;
    int x = v;
    #pragma unroll
    for (int off = 1; off < 64; off <<= 1) {
        int y = __shfl_up(x, off, 64);
        if (lane >= off) x += y;
    }
    if (lane == 63) wt[wid] = x;
    __syncthreads();
    if (t == 0) {
        int s = 0;
        #pragma unroll
        for (int j = 0; j < 4; ++j) { int tv = wt[j]; wt[j] = s; s += tv; }
    }
    __syncthreads();
    if (t < SCAN_NB) bsums[t] = wt[wid] + x - v;
}

__global__ void add_off_kernel(int* __restrict__ rowptr, int* __restrict__ cursor,
                               const int* __restrict__ bsums) {
    int i = blockIdx.x * 256 + threadIdx.x;
    if (i < N_NODES) {
        int r = rowptr[i] + bsums[blockIdx.x];
        rowptr[i] = r;
        cursor[i] = r;
    }
    if (i == 0) rowptr[N_NODES] = N_EDGES + N_NODES;
}

// colx stores BYTE offsets into the fp8 xl matrix: s * HCDIM (256 B rows)
__global__ void fill_kernel(const int* __restrict__ ei, int* __restrict__ cursor,
                            int* __restrict__ colx) {
    int i = blockIdx.x * 256 + threadIdx.x;
    int total = N_EDGES + N_NODES;
    if (i >= total) return;
    int s, d;
    if (i < N_EDGES) { s = ei[i]; d = ei[N_EDGES + i]; }
    else             { s = i - N_EDGES; d = s; }
    int pos = atomicAdd(&cursor[d], 1);
    colx[pos] = s * HCDIM;
}

// ============================ Fused prep: x->fp16, pad zero, W->fp16 n-major ============================
__global__ void prep_kernel(const float* __restrict__ x, _Float16* __restrict__ A,
                            _Float16* __restrict__ Bt0, _Float16* __restrict__ Bt1,
                            _Float16* __restrict__ Bt2,
                            const float* __restrict__ Wl0, const float* __restrict__ Wr0,
                            const float* __restrict__ Wl1, const float* __restrict__ Wr1,
                            const float* __restrict__ Wl2, const float* __restrict__ Wr2) {
    int b = blockIdx.x;
    if (b < SPLITX_NB) {
        int base = (b * 256 + threadIdx.x) * 4;
        int row = base >> 7;
        float4 v = make_float4(0.f, 0.f, 0.f, 0.f);
        if (row < N_NODES) v = *(const float4*)&x[base];
        f16x4 o;
        o.x = (_Float16)v.x; o.y = (_Float16)v.y; o.z = (_Float16)v.z; o.w = (_Float16)v.w;
        *(f16x4*)&A[base] = o;
    } else if (b < SPLITX_NB + ZERO_NB) {
        int i = ((b - SPLITX_NB) * 256 + threadIdx.x) * 4;
        if (i < (MPAD - N_NODES) * HCDIM) {
            f16x4 z = {(_Float16)0.f, (_Float16)0.f, (_Float16)0.f, (_Float16)0.f};
            *(f16x4*)&A[(size_t)N_NODES * HCDIM + i] = z;
        }
    } else {
        int t = (b - SPLITX_NB - ZERO_NB) * 256 + threadIdx.x;
        const float* Wl; const float* Wr; _Float16* Bt; int K;
        if (t < 512 * F_INPUT)            { Wl = Wl0; Wr = Wr0; Bt = Bt0; K = F_INPUT; }
        else if (t < 512 * (F_INPUT + HCDIM)) { t -= 512 * F_INPUT; Wl = Wl1; Wr = Wr1; Bt = Bt1; K = HCDIM; }
        else                              { t -= 512 * (F_INPUT + HCDIM); Wl = Wl2; Wr = Wr2; Bt = Bt2; K = HCDIM; }
        int n = t & 511, k = t >> 9;
        float w = (n < 256) ? Wl[k * 256 + n] : Wr[k * 256 + (n - 256)];
        Bt[n * K + k] = (_Float16)w;
    }
}

// ============================ fp16 MFMA GEMM, BK=64 ============================
__global__ __launch_bounds__(256) void gemm_mfma(
    const _Float16* __restrict__ A, const _Float16* __restrict__ B,
    int K,
    const float* __restrict__ bl, const float* __restrict__ br,
    unsigned char* __restrict__ xl8, _Float16* __restrict__ xrh)
{
    __shared__ _Float16 sA[128 * 64], sB[128 * 64];
    int tid = threadIdx.x;
    int lane = tid & 63, wave = tid >> 6;
    int wm = wave >> 1, wn = wave & 1;
    int bx = blockIdx.x >> 2, by = blockIdx.x & 3;
    int row0 = bx * 128;
    int n0 = by * 128;
    int quad = lane >> 4, l16 = lane & 15;

    f32x4 acc[4][4];
    #pragma unroll
    for (int i = 0; i < 4; ++i)
        #pragma unroll
        for (int j = 0; j < 4; ++j)
            acc[i][j] = (f32x4){0.f, 0.f, 0.f, 0.f};

    for (int k0 = 0; k0 < K; k0 += 64) {
        __syncthreads();
        #pragma unroll
        for (int pass = 0; pass < 4; ++pass) {
            int c = tid + pass * 256;           // chunk 0..1023 (16 B each)
            int r = c >> 3;                     // tile row
            int pl = c & 7;                     // physical k-chunk in LDS row
            int pg = pl ^ (r & 7);              // global k-chunk (swizzled)
            size_t ga = (size_t)(row0 + r) * K + k0 + pg * 8;
            size_t gb = (size_t)(n0 + r) * K + k0 + pg * 8;
            gl_lds16(A + ga, sA + c * 8);
            gl_lds16(B + gb, sB + c * 8);
        }
        __syncthreads();

        #pragma unroll
        for (int kk = 0; kk < 2; ++kk) {
            f16x8 fa[4], fb[4];
            #pragma unroll
            for (int i = 0; i < 4; ++i) {
                int rr = wm * 64 + i * 16 + l16;
                int ca = (kk * 4 + quad) ^ (rr & 7);
                fa[i] = *(const f16x8*)&sA[rr * 64 + ca * 8];
                int nn = wn * 64 + i * 16 + l16;
                int cb = (kk * 4 + quad) ^ (nn & 7);
                fb[i] = *(const f16x8*)&sB[nn * 64 + cb * 8];
            }
            #pragma unroll
            for (int i = 0; i < 4; ++i)
                #pragma unroll
                for (int j = 0; j < 4; ++j)
                    acc[i][j] = __builtin_amdgcn_mfma_f32_16x16x32_f16(fa[i], fb[j], acc[i][j], 0, 0, 0);
        }
    }

    if (by < 2) {
        int cb0 = by * 128;
        #pragma unroll
        for (int j = 0; j < 4; ++j) {
            int col = cb0 + wn * 64 + j * 16 + l16;
            float bj = bl[col];
            #pragma unroll
            for (int i = 0; i < 4; ++i) {
                int rbase = row0 + wm * 64 + i * 16 + quad * 4;
                #pragma unroll
                for (int r = 0; r < 4; ++r) {
                    int row = rbase + r;
                    if (row < N_NODES) {
                        float v = acc[i][j][r] + bj;
                        int pk = __builtin_amdgcn_cvt_pk_fp8_f32(v, v, 0, false);
                        xl8[(size_t)row * HCDIM + col] = (unsigned char)pk;
                    }
                }
            }
        }
    } else {
        int cb0 = (by - 2) * 128;
        #pragma unroll
        for (int j = 0; j < 4; ++j) {
            int col = cb0 + wn * 64 + j * 16 + l16;
            float bj = br[col];
            #pragma unroll
            for (int i = 0; i < 4; ++i) {
                int rbase = row0 + wm * 64 + i * 16 + quad * 4;
                #pragma unroll
                for (int r = 0; r < 4; ++r) {
                    int row = rbase + r;
                    if (row < N_NODES)
                        xrh[(size_t)row * HCDIM + col] = (_Float16)(acc[i][j][r] + bj);
                }
            }
        }
    }
}

// ============================ Edge phase: fp8 gather, no-max exp2 softmax, 4-edge unroll ============================
// Softmax without running max: scores are O(+-10) (att ~ N(0,1/sqrt(C)), activations O(1)), and
// fp32 exp2 overflows only past 2^127 — so w = e^p directly; ratio w/denom is the exact softmax.
// This removes the loop-carried m/corr recurrence; accumulation is plain independent adds,
// enabling a 4-edge unroll with 8 gathers in flight (d[4] prefetch nd[4]).
__global__ __launch_bounds__(256) void gat_edge(
    const unsigned char* __restrict__ xl8, const _Float16* __restrict__ xrh,
    const float* __restrict__ att, const float* __restrict__ bias,
    const int* __restrict__ rowptr, const int* __restrict__ colx,
    _Float16* __restrict__ outh, _Float16* __restrict__ onext, int mode)
{
    int wave = threadIdx.x >> 6;
    int lane = threadIdx.x & 63;
    int node = blockIdx.x * 4 + wave;
    if (node >= N_NODES) return;
    int lb8  = lane * 4;                     // byte offset within fp8 row
    int lb16 = lane * 8;                     // byte offset within fp16 row
    const char* xlb = (const char*)xl8;

    uint2 xrr = *(const uint2*)((const char*)xrh + (size_t)node * (HCDIM * 2) + lb16);
    h2 xra = bch2(xrr.x), xrb = bch2(xrr.y);
    float4 at4 = *(const float4*)&att[lane * 4];
    h2 ata = {(_Float16)at4.x, (_Float16)at4.y};
    h2 atb = {(_Float16)at4.z, (_Float16)at4.w};

    int e0 = rowptr[node], e1 = rowptr[node + 1];
    int elast = e1 - 1;                      // >= e0 (self-loop guarantees deg>=1)
    float denom = 0.f;
    float4 acc = make_float4(0.f, 0.f, 0.f, 0.f);

    unsigned int d[4];
    #pragma unroll
    for (int k = 0; k < 4; ++k) {
        int ee = e0 + k; ee = ee < e1 ? ee : elast;
        d[k] = *(const unsigned int*)(xlb + (size_t)(unsigned)colx[ee] + lb8);
    }

    for (int e = e0; e < e1; e += 4) {
        unsigned int nd[4];
        #pragma unroll
        for (int k = 0; k < 4; ++k) {
            int ee = e + 4 + k; ee = ee < e1 ? ee : elast;
            nd[k] = *(const unsigned int*)(xlb + (size_t)(unsigned)colx[ee] + lb8);
        }

        f32x2 lo[4], hi[4];
        float p[4];
        #pragma unroll
        for (int k = 0; k < 4; ++k) {
            lo[k] = __builtin_amdgcn_cvt_pk_f32_fp8(d[k], false);
            hi[k] = __builtin_amdgcn_cvt_pk_f32_fp8(d[k], true);
            h2 a = pk16(lo[k].x, lo[k].y);
            h2 b = pk16(hi[k].x, hi[k].y);
            h2 la = lrelu2(a + xra);
            h2 lbv = lrelu2(b + xrb);
            float pp = __builtin_amdgcn_fdot2(la, ata, 0.f, false);
            p[k] = __builtin_amdgcn_fdot2(lbv, atb, pp, false);
        }
        #pragma unroll
        for (int off = 1; off <= 8; off <<= 1) {
            #pragma unroll
            for (int k = 0; k < 4; ++k) p[k] += __shfl_xor(p[k], off, 64);
        }
        float w[4];
        #pragma unroll
        for (int k = 0; k < 4; ++k)
            w[k] = (e + k < e1) ? exp2f(p[k] * LOG2E) : 0.f;

        denom += (w[0] + w[1]) + (w[2] + w[3]);
        acc.x += w[0] * lo[0].x + w[1] * lo[1].x + w[2] * lo[2].x + w[3] * lo[3].x;
        acc.y += w[0] * lo[0].y + w[1] * lo[1].y + w[2] * lo[2].y + w[3] * lo[3].y;
        acc.z += w[0] * hi[0].x + w[1] * hi[1].x + w[2] * hi[2].x + w[3] * hi[3].x;
        acc.w += w[0] * hi[0].y + w[1] * hi[1].y + w[2] * hi[2].y + w[3] * hi[3].y;
        d[0] = nd[0]; d[1] = nd[1]; d[2] = nd[2]; d[3] = nd[3];
    }

    float inv = 1.f / denom;
    float4 b4 = *(const float4*)&bias[lane * 4];
    float ox = acc.x * inv + b4.x;
    float oy = acc.y * inv + b4.y;
    float oz = acc.z * inv + b4.z;
    float ow = acc.w * inv + b4.w;
    if (mode == 0) {
        f16x4 h;
        h.x = (_Float16)ox; h.y = (_Float16)oy;
        h.z = (_Float16)oz; h.w = (_Float16)ow;
        *(f16x4*)((char*)outh + (size_t)node * (HCDIM * 2) + lb16) = h;
    } else {
        f16x4 h;
        h.x = (_Float16)fmaxf(ox, 0.f); h.y = (_Float16)fmaxf(oy, 0.f);
        h.z = (_Float16)fmaxf(oz, 0.f); h.w = (_Float16)fmaxf(ow, 0.f);
        *(f16x4*)((char*)onext + (size_t)node * (HCDIM * 2) + lb16) = h;
    }
}

// ============================ Pooling (fp16 input) ============================
__global__ __launch_bounds__(256) void pool_kernel(
    const _Float16* __restrict__ h, const int* __restrict__ startg,
    const int* __restrict__ endg, float* __restrict__ p)
{
    __shared__ float4 sS[4][64];
    __shared__ float4 sM[4][64];
    int g = blockIdx.x;
    int lane = threadIdx.x & 63;
    int sub = threadIdx.x >> 6;
    int c0 = lane * 4;
    int s = startg[g], e = endg[g];
    float4 sum = make_float4(0.f, 0.f, 0.f, 0.f);
    float4 mx = make_float4(-INFINITY, -INFINITY, -INFINITY, -INFINITY);
    for (int i = s + sub; i < e; i += 4) {
        uint2 u = *(const uint2*)&h[(size_t)i * HCDIM + c0];
        h2 a = bch2(u.x), b = bch2(u.y);
        float4 v = make_float4((float)a.x, (float)a.y, (float)b.x, (float)b.y);
        sum.x += v.x; sum.y += v.y; sum.z += v.z; sum.w += v.w;
        mx.x = fmaxf(mx.x, v.x); mx.y = fmaxf(mx.y, v.y);
        mx.z = fmaxf(mx.z, v.z); mx.w = fmaxf(mx.w, v.w);
    }
    sS[sub][lane] = sum; sM[sub][lane] = mx;
    __syncthreads();
    if (sub == 0) {
        #pragma unroll
        for (int j = 1; j < 4; ++j) {
            float4 a = sS[j][lane], b = sM[j][lane];
            sum.x += a.x; sum.y += a.y; sum.z += a.z; sum.w += a.w;
            mx.x = fmaxf(mx.x, b.x); mx.y = fmaxf(mx.y, b.y);
            mx.z = fmaxf(mx.z, b.z); mx.w = fmaxf(mx.w, b.w);
        }
        int cnt = e - s;
        float inv = 1.f / fmaxf((float)cnt, 1.f);
        float4 o;
        o.x = sum.x * inv + mx.x; o.y = sum.y * inv + mx.y;
        o.z = sum.z * inv + mx.z; o.w = sum.w * inv + mx.w;
        *(float4*)&p[(size_t)g * HCDIM + c0] = o;
    }
}

// ============================ Head: logits + softmax ============================
__global__ void logits_kernel(const float* __restrict__ p, const float* __restrict__ Wout,
                              const float* __restrict__ bout, float* __restrict__ out)
{
    __shared__ float red[256];
    __shared__ float lg[NCLS];
    int g = blockIdx.x, t = threadIdx.x;
    float pv = p[g * HCDIM + t];
    for (int j = 0; j < NCLS; ++j) {
        red[t] = pv * Wout[t * NCLS + j];
        __syncthreads();
        for (int off = 128; off > 0; off >>= 1) {
            if (t < off) red[t] += red[t + off];
            __syncthreads();
        }
        if (t == 0) lg[j] = red[0] + bout[j];
        __syncthreads();
    }
    if (t == 0) {
        float mx = fmaxf(lg[0], fmaxf(lg[1], lg[2]));
        float e0 = __expf(lg[0] - mx), e1 = __expf(lg[1] - mx), e2 = __expf(lg[2] - mx);
        float inv = 1.f / (e0 + e1 + e2);
        out[g * NCLS + 0] = e0 * inv;
        out[g * NCLS + 1] = e1 * inv;
        out[g * NCLS + 2] = e2 * inv;
    }
}

// ============================ Orchestration ============================
extern "C" void kernel_launch(void* const* d_in, const int* in_sizes, int n_in,
                              void* d_out, int out_size, void* d_ws, size_t ws_size,
                              hipStream_t stream) {
    const float* x     = (const float*)d_in[0];
    const int*   ei    = (const int*)d_in[1];
    const int*   batch = (const int*)d_in[2];
    const float *Wl[3], *bl[3], *Wr[3], *br[3], *att[3], *bias[3];
    for (int li = 0; li < 3; ++li) {
        int b = 3 + li * 6;
        Wl[li]   = (const float*)d_in[b + 0];
        bl[li]   = (const float*)d_in[b + 1];
        Wr[li]   = (const float*)d_in[b + 2];
        br[li]   = (const float*)d_in[b + 3];
        att[li]  = (const float*)d_in[b + 4];
        bias[li] = (const float*)d_in[b + 5];
    }
    const float* Wout = (const float*)d_in[21];
    const float* bout = (const float*)d_in[22];
    float* out = (float*)d_out;

    size_t off = 0;
    char* wsb = (char*)d_ws;
    auto alloc = [&](size_t bytes) -> char* {
        char* ptr = wsb + off;
        off += (bytes + 255) & ~(size_t)255;
        return ptr;
    };
    // deg + startg + endg in one zero-init block (single memset)
    int* zblk    = (int*)alloc((N_NODES + 2 * NGRAPH) * sizeof(int));
    int* deg     = zblk;
    int* startg  = zblk + N_NODES;
    int* endg    = zblk + N_NODES + NGRAPH;
    int* rowptr  = (int*)alloc((N_NODES + 1) * sizeof(int));
    int* cursor  = (int*)alloc(N_NODES * sizeof(int));
    int* bsums   = (int*)alloc(256 * sizeof(int));
    int* colx    = (int*)alloc((size_t)(N_EDGES + N_NODES) * sizeof(int));
    _Float16* Abuf = (_Float16*)alloc((size_t)MPAD * HCDIM * sizeof(_Float16));
    _Float16* Bt[3];
    for (int li = 0; li < 3; ++li) {
        int K = (li == 0) ? F_INPUT : HCDIM;
        Bt[li] = (_Float16*)alloc((size_t)512 * K * sizeof(_Float16));
    }
    unsigned char* xl8 = (unsigned char*)alloc((size_t)N_NODES * HCDIM);
    _Float16* xrh  = (_Float16*)alloc((size_t)N_NODES * HCDIM * sizeof(_Float16));
    _Float16* hbuf = (_Float16*)alloc((size_t)N_NODES * HCDIM * sizeof(_Float16));
    float* pbuf    = (float*)alloc((size_t)NGRAPH * HCDIM * sizeof(float));

    hipMemsetAsync(zblk, 0, (N_NODES + 2 * NGRAPH) * sizeof(int), stream);

    hist_boundary_kernel<<<HIST_NB + BND_NB, 256, 0, stream>>>(ei, deg, batch, startg, endg);
    block_scan_kernel<<<SCAN_NB, 256, 0, stream>>>(deg, rowptr, bsums);
    scan_bsums_kernel<<<1, 256, 0, stream>>>(bsums);
    add_off_kernel<<<SCAN_NB, 256, 0, stream>>>(rowptr, cursor, bsums);
    fill_kernel<<<(N_EDGES + N_NODES + 255) / 256, 256, 0, stream>>>(ei, cursor, colx);

    prep_kernel<<<PREP_NB, 256, 0, stream>>>(x, Abuf, Bt[0], Bt[1], Bt[2],
                                             Wl[0], Wr[0], Wl[1], Wr[1], Wl[2], Wr[2]);

    for (int li = 0; li < 3; ++li) {
        int K = (li == 0) ? F_INPUT : HCDIM;
        gemm_mfma<<<(MPAD / 128) * 4, 256, 0, stream>>>(
            Abuf, Bt[li], K, bl[li], br[li], xl8, xrh);
        if (li < 2) {
            gat_edge<<<N_NODES / 4, 256, 0, stream>>>(
                xl8, xrh, att[li], bias[li], rowptr, colx, nullptr, Abuf, 1);
        } else {
            gat_edge<<<N_NODES / 4, 256, 0, stream>>>(
                xl8, xrh, att[li], bias[li], rowptr, colx, hbuf, nullptr, 0);
        }
    }

    pool_kernel<<<NGRAPH, 256, 0, stream>>>(hbuf, startg, endg, pbuf);
    logits_kernel<<<NGRAPH, 256, 0, stream>>>(pbuf, Wout, bout, out);
}

// Round 11
// 569.243 us; speedup vs baseline: 1.1255x; 1.0633x over previous
//
#include <hip/hip_runtime.h>
#include <math.h>

#define N_NODES 50000
#define N_EDGES 600000
#define F_INPUT 128
#define HCDIM 256
#define NGRAPH 64
#define NCLS 3
#define MPAD 50048   // 391 * 128, GEMM M padded
#define SCAN_NB ((N_NODES + 255) / 256)   // 196
#define LOG2E 1.4426950408889634f

// fused prep kernel block ranges
#define SPLITX_NB (MPAD * F_INPUT / 4 / 256)            // 6256
#define ZERO_NB   (((MPAD - N_NODES) * HCDIM / 4 + 255) / 256)  // 12
#define WPREP_NB  (512 * (F_INPUT + HCDIM + HCDIM) / 256)       // 1280
#define PREP_NB   (SPLITX_NB + ZERO_NB + WPREP_NB)
// fused hist+boundary ranges
#define HIST_NB   ((N_EDGES + N_NODES + 255) / 256)     // 2540
#define BND_NB    ((N_NODES + 255) / 256)               // 196

typedef float f32x4 __attribute__((ext_vector_type(4)));
typedef float f32x2 __attribute__((ext_vector_type(2)));
typedef _Float16 f16x8 __attribute__((ext_vector_type(8)));
typedef _Float16 f16x4 __attribute__((ext_vector_type(4)));
typedef _Float16 h2 __attribute__((ext_vector_type(2)));

__device__ __forceinline__ void gl_lds16(const void* g, void* l) {
    __builtin_amdgcn_global_load_lds(
        (const __attribute__((address_space(1))) unsigned int*)g,
        (__attribute__((address_space(3))) unsigned int*)l, 16, 0, 0);
}

__device__ __forceinline__ h2 bch2(unsigned int u) { return __builtin_bit_cast(h2, u); }
__device__ __forceinline__ h2 pk16(float a, float b) {
    return __builtin_bit_cast(h2, __builtin_amdgcn_cvt_pkrtz(a, b));
}

// packed leaky_relu(0.2): max(v,0) + 0.2*min(v,0)
__device__ __forceinline__ h2 lrelu2(h2 v) {
    const h2 z = {(_Float16)0.f, (_Float16)0.f};
    const h2 c = {(_Float16)0.2f, (_Float16)0.2f};
    h2 mx = __builtin_elementwise_max(v, z);
    h2 mn = __builtin_elementwise_min(v, z);
    return mx + mn * c;
}

// ============================ hist + boundary (fused) ============================
__global__ void hist_boundary_kernel(const int* __restrict__ ei, int* __restrict__ deg,
                                     const int* __restrict__ batch,
                                     int* __restrict__ startg, int* __restrict__ endg) {
    int b = blockIdx.x;
    if (b < HIST_NB) {
        int i = b * 256 + threadIdx.x;
        int total = N_EDGES + N_NODES;
        if (i >= total) return;
        int d = (i < N_EDGES) ? ei[N_EDGES + i] : (i - N_EDGES);
        atomicAdd(&deg[d], 1);
    } else {
        int i = (b - HIST_NB) * 256 + threadIdx.x;
        if (i >= N_NODES) return;
        int g = batch[i];
        if (i == 0 || batch[i - 1] != g) startg[g] = i;
        if (i == N_NODES - 1 || batch[i + 1] != g) endg[g] = i + 1;
    }
}

// ============================ CSR scan ============================
__global__ void block_scan_kernel(const int* __restrict__ deg, int* __restrict__ rowptr,
                                  int* __restrict__ bsums) {
    __shared__ int wt[4];
    int b = blockIdx.x, t = threadIdx.x, lane = t & 63, wid = t >> 6;
    int i = b * 256 + t;
    int v = (i < N_NODES) ? deg[i] : 0;
    int x = v;
    #pragma unroll
    for (int off = 1; off < 64; off <<= 1) {
        int y = __shfl_up(x, off, 64);
        if (lane >= off) x += y;
    }
    if (lane == 63) wt[wid] = x;
    __syncthreads();
    if (t == 0) {
        int s = 0;
        #pragma unroll
        for (int j = 0; j < 4; ++j) { int tv = wt[j]; wt[j] = s; s += tv; }
        bsums[b] = s;
    }
    __syncthreads();
    if (i < N_NODES) rowptr[i] = wt[wid] + x - v;
}

__global__ void scan_bsums_kernel(int* __restrict__ bsums) {
    __shared__ int wt[4];
    int t = threadIdx.x, lane = t & 63, wid = t >> 6;
    int v = (t < SCAN_NB) ? bsums[t] : 0;
    int x = v;
    #pragma unroll
    for (int off = 1; off < 64; off <<= 1) {
        int y = __shfl_up(x, off, 64);
        if (lane >= off) x += y;
    }
    if (lane == 63) wt[wid] = x;
    __syncthreads();
    if (t == 0) {
        int s = 0;
        #pragma unroll
        for (int j = 0; j < 4; ++j) { int tv = wt[j]; wt[j] = s; s += tv; }
    }
    __syncthreads();
    if (t < SCAN_NB) bsums[t] = wt[wid] + x - v;
}

__global__ void add_off_kernel(int* __restrict__ rowptr, int* __restrict__ cursor,
                               const int* __restrict__ bsums) {
    int i = blockIdx.x * 256 + threadIdx.x;
    if (i < N_NODES) {
        int r = rowptr[i] + bsums[blockIdx.x];
        rowptr[i] = r;
        cursor[i] = r;
    }
    if (i == 0) rowptr[N_NODES] = N_EDGES + N_NODES;
}

// colx stores BYTE offsets into the fp8 xl matrix: s * HCDIM (256 B rows).
// Entries [total, total+8) are zero padding so the edge loop needs no prefetch clamps.
__global__ void fill_kernel(const int* __restrict__ ei, int* __restrict__ cursor,
                            int* __restrict__ colx) {
    int i = blockIdx.x * 256 + threadIdx.x;
    int total = N_EDGES + N_NODES;
    if (i >= total + 8) return;
    if (i >= total) { colx[i] = 0; return; }
    int s, d;
    if (i < N_EDGES) { s = ei[i]; d = ei[N_EDGES + i]; }
    else             { s = i - N_EDGES; d = s; }
    int pos = atomicAdd(&cursor[d], 1);
    colx[pos] = s * HCDIM;
}

// ============================ Fused prep: x->fp16, pad zero, W->fp16 n-major ============================
__global__ void prep_kernel(const float* __restrict__ x, _Float16* __restrict__ A,
                            _Float16* __restrict__ Bt0, _Float16* __restrict__ Bt1,
                            _Float16* __restrict__ Bt2,
                            const float* __restrict__ Wl0, const float* __restrict__ Wr0,
                            const float* __restrict__ Wl1, const float* __restrict__ Wr1,
                            const float* __restrict__ Wl2, const float* __restrict__ Wr2) {
    int b = blockIdx.x;
    if (b < SPLITX_NB) {
        int base = (b * 256 + threadIdx.x) * 4;
        int row = base >> 7;
        float4 v = make_float4(0.f, 0.f, 0.f, 0.f);
        if (row < N_NODES) v = *(const float4*)&x[base];
        f16x4 o;
        o.x = (_Float16)v.x; o.y = (_Float16)v.y; o.z = (_Float16)v.z; o.w = (_Float16)v.w;
        *(f16x4*)&A[base] = o;
    } else if (b < SPLITX_NB + ZERO_NB) {
        int i = ((b - SPLITX_NB) * 256 + threadIdx.x) * 4;
        if (i < (MPAD - N_NODES) * HCDIM) {
            f16x4 z = {(_Float16)0.f, (_Float16)0.f, (_Float16)0.f, (_Float16)0.f};
            *(f16x4*)&A[(size_t)N_NODES * HCDIM + i] = z;
        }
    } else {
        int t = (b - SPLITX_NB - ZERO_NB) * 256 + threadIdx.x;
        const float* Wl; const float* Wr; _Float16* Bt; int K;
        if (t < 512 * F_INPUT)            { Wl = Wl0; Wr = Wr0; Bt = Bt0; K = F_INPUT; }
        else if (t < 512 * (F_INPUT + HCDIM)) { t -= 512 * F_INPUT; Wl = Wl1; Wr = Wr1; Bt = Bt1; K = HCDIM; }
        else                              { t -= 512 * (F_INPUT + HCDIM); Wl = Wl2; Wr = Wr2; Bt = Bt2; K = HCDIM; }
        int n = t & 511, k = t >> 9;
        float w = (n < 256) ? Wl[k * 256 + n] : Wr[k * 256 + (n - 256)];
        Bt[n * K + k] = (_Float16)w;
    }
}

// ============================ fp16 MFMA GEMM, BK=64 ============================
__global__ __launch_bounds__(256) void gemm_mfma(
    const _Float16* __restrict__ A, const _Float16* __restrict__ B,
    int K,
    const float* __restrict__ bl, const float* __restrict__ br,
    unsigned char* __restrict__ xl8, _Float16* __restrict__ xrh)
{
    __shared__ _Float16 sA[128 * 64], sB[128 * 64];
    int tid = threadIdx.x;
    int lane = tid & 63, wave = tid >> 6;
    int wm = wave >> 1, wn = wave & 1;
    int bx = blockIdx.x >> 2, by = blockIdx.x & 3;
    int row0 = bx * 128;
    int n0 = by * 128;
    int quad = lane >> 4, l16 = lane & 15;

    f32x4 acc[4][4];
    #pragma unroll
    for (int i = 0; i < 4; ++i)
        #pragma unroll
        for (int j = 0; j < 4; ++j)
            acc[i][j] = (f32x4){0.f, 0.f, 0.f, 0.f};

    for (int k0 = 0; k0 < K; k0 += 64) {
        __syncthreads();
        #pragma unroll
        for (int pass = 0; pass < 4; ++pass) {
            int c = tid + pass * 256;           // chunk 0..1023 (16 B each)
            int r = c >> 3;                     // tile row
            int pl = c & 7;                     // physical k-chunk in LDS row
            int pg = pl ^ (r & 7);              // global k-chunk (swizzled)
            size_t ga = (size_t)(row0 + r) * K + k0 + pg * 8;
            size_t gb = (size_t)(n0 + r) * K + k0 + pg * 8;
            gl_lds16(A + ga, sA + c * 8);
            gl_lds16(B + gb, sB + c * 8);
        }
        __syncthreads();

        #pragma unroll
        for (int kk = 0; kk < 2; ++kk) {
            f16x8 fa[4], fb[4];
            #pragma unroll
            for (int i = 0; i < 4; ++i) {
                int rr = wm * 64 + i * 16 + l16;
                int ca = (kk * 4 + quad) ^ (rr & 7);
                fa[i] = *(const f16x8*)&sA[rr * 64 + ca * 8];
                int nn = wn * 64 + i * 16 + l16;
                int cb = (kk * 4 + quad) ^ (nn & 7);
                fb[i] = *(const f16x8*)&sB[nn * 64 + cb * 8];
            }
            #pragma unroll
            for (int i = 0; i < 4; ++i)
                #pragma unroll
                for (int j = 0; j < 4; ++j)
                    acc[i][j] = __builtin_amdgcn_mfma_f32_16x16x32_f16(fa[i], fb[j], acc[i][j], 0, 0, 0);
        }
    }

    if (by < 2) {
        int cb0 = by * 128;
        #pragma unroll
        for (int j = 0; j < 4; ++j) {
            int col = cb0 + wn * 64 + j * 16 + l16;
            float bj = bl[col];
            #pragma unroll
            for (int i = 0; i < 4; ++i) {
                int rbase = row0 + wm * 64 + i * 16 + quad * 4;
                #pragma unroll
                for (int r = 0; r < 4; ++r) {
                    int row = rbase + r;
                    if (row < N_NODES) {
                        float v = acc[i][j][r] + bj;
                        int pk = __builtin_amdgcn_cvt_pk_fp8_f32(v, v, 0, false);
                        xl8[(size_t)row * HCDIM + col] = (unsigned char)pk;
                    }
                }
            }
        }
    } else {
        int cb0 = (by - 2) * 128;
        #pragma unroll
        for (int j = 0; j < 4; ++j) {
            int col = cb0 + wn * 64 + j * 16 + l16;
            float bj = br[col];
            #pragma unroll
            for (int i = 0; i < 4; ++i) {
                int rbase = row0 + wm * 64 + i * 16 + quad * 4;
                #pragma unroll
                for (int r = 0; r < 4; ++r) {
                    int row = rbase + r;
                    if (row < N_NODES)
                        xrh[(size_t)row * HCDIM + col] = (_Float16)(acc[i][j][r] + bj);
                }
            }
        }
    }
}

// ============================ Edge phase: fp8 gather, no-max exp2 softmax, lean 4-edge unroll ============================
// colx is padded (+8 zeros) so prefetch needs no clamps; att pre-scaled by log2(e) so
// exp2 consumes scores directly. Out-of-range prefetches read node 0's row, masked by w=0.
__global__ __launch_bounds__(256) void gat_edge(
    const unsigned char* __restrict__ xl8, const _Float16* __restrict__ xrh,
    const float* __restrict__ att, const float* __restrict__ bias,
    const int* __restrict__ rowptr, const int* __restrict__ colx,
    _Float16* __restrict__ outh, _Float16* __restrict__ onext, int mode)
{
    int wave = threadIdx.x >> 6;
    int lane = threadIdx.x & 63;
    int node = blockIdx.x * 4 + wave;
    if (node >= N_NODES) return;
    int lb8  = lane * 4;                     // byte offset within fp8 row
    int lb16 = lane * 8;                     // byte offset within fp16 row
    const char* xlb = (const char*)xl8;

    uint2 xrr = *(const uint2*)((const char*)xrh + (size_t)node * (HCDIM * 2) + lb16);
    h2 xra = bch2(xrr.x), xrb = bch2(xrr.y);
    float4 at4 = *(const float4*)&att[lane * 4];
    // pre-scale attention by log2(e): scores come out ready for exp2
    h2 ata = {(_Float16)(at4.x * LOG2E), (_Float16)(at4.y * LOG2E)};
    h2 atb = {(_Float16)(at4.z * LOG2E), (_Float16)(at4.w * LOG2E)};

    int e0 = rowptr[node], e1 = rowptr[node + 1];
    float denom = 0.f;
    float4 acc = make_float4(0.f, 0.f, 0.f, 0.f);

    unsigned int d[4];
    #pragma unroll
    for (int k = 0; k < 4; ++k)
        d[k] = *(const unsigned int*)(xlb + (size_t)(unsigned)colx[e0 + k] + lb8);

    for (int e = e0; e < e1; e += 4) {
        unsigned int nd[4];
        #pragma unroll
        for (int k = 0; k < 4; ++k)
            nd[k] = *(const unsigned int*)(xlb + (size_t)(unsigned)colx[e + 4 + k] + lb8);

        f32x2 lo[4], hi[4];
        float p[4];
        #pragma unroll
        for (int k = 0; k < 4; ++k) {
            lo[k] = __builtin_amdgcn_cvt_pk_f32_fp8(d[k], false);
            hi[k] = __builtin_amdgcn_cvt_pk_f32_fp8(d[k], true);
            h2 a = pk16(lo[k].x, lo[k].y);
            h2 b = pk16(hi[k].x, hi[k].y);
            h2 la = lrelu2(a + xra);
            h2 lbv = lrelu2(b + xrb);
            float pp = __builtin_amdgcn_fdot2(la, ata, 0.f, false);
            p[k] = __builtin_amdgcn_fdot2(lbv, atb, pp, false);
        }
        #pragma unroll
        for (int off = 1; off <= 8; off <<= 1) {
            #pragma unroll
            for (int k = 0; k < 4; ++k) p[k] += __shfl_xor(p[k], off, 64);
        }
        float w[4];
        #pragma unroll
        for (int k = 0; k < 4; ++k)
            w[k] = (e + k < e1) ? exp2f(p[k]) : 0.f;

        denom += (w[0] + w[1]) + (w[2] + w[3]);
        acc.x += w[0] * lo[0].x + w[1] * lo[1].x + w[2] * lo[2].x + w[3] * lo[3].x;
        acc.y += w[0] * lo[0].y + w[1] * lo[1].y + w[2] * lo[2].y + w[3] * lo[3].y;
        acc.z += w[0] * hi[0].x + w[1] * hi[1].x + w[2] * hi[2].x + w[3] * hi[3].x;
        acc.w += w[0] * hi[0].y + w[1] * hi[1].y + w[2] * hi[2].y + w[3] * hi[3].y;
        d[0] = nd[0]; d[1] = nd[1]; d[2] = nd[2]; d[3] = nd[3];
    }

    float inv = 1.f / denom;
    float4 b4 = *(const float4*)&bias[lane * 4];
    float ox = acc.x * inv + b4.x;
    float oy = acc.y * inv + b4.y;
    float oz = acc.z * inv + b4.z;
    float ow = acc.w * inv + b4.w;
    if (mode == 0) {
        f16x4 h;
        h.x = (_Float16)ox; h.y = (_Float16)oy;
        h.z = (_Float16)oz; h.w = (_Float16)ow;
        *(f16x4*)((char*)outh + (size_t)node * (HCDIM * 2) + lb16) = h;
    } else {
        f16x4 h;
        h.x = (_Float16)fmaxf(ox, 0.f); h.y = (_Float16)fmaxf(oy, 0.f);
        h.z = (_Float16)fmaxf(oz, 0.f); h.w = (_Float16)fmaxf(ow, 0.f);
        *(f16x4*)((char*)onext + (size_t)node * (HCDIM * 2) + lb16) = h;
    }
}

// ============================ Pooling (fp16 input) ============================
__global__ __launch_bounds__(256) void pool_kernel(
    const _Float16* __restrict__ h, const int* __restrict__ startg,
    const int* __restrict__ endg, float* __restrict__ p)
{
    __shared__ float4 sS[4][64];
    __shared__ float4 sM[4][64];
    int g = blockIdx.x;
    int lane = threadIdx.x & 63;
    int sub = threadIdx.x >> 6;
    int c0 = lane * 4;
    int s = startg[g], e = endg[g];
    float4 sum = make_float4(0.f, 0.f, 0.f, 0.f);
    float4 mx = make_float4(-INFINITY, -INFINITY, -INFINITY, -INFINITY);
    for (int i = s + sub; i < e; i += 4) {
        uint2 u = *(const uint2*)&h[(size_t)i * HCDIM + c0];
        h2 a = bch2(u.x), b = bch2(u.y);
        float4 v = make_float4((float)a.x, (float)a.y, (float)b.x, (float)b.y);
        sum.x += v.x; sum.y += v.y; sum.z += v.z; sum.w += v.w;
        mx.x = fmaxf(mx.x, v.x); mx.y = fmaxf(mx.y, v.y);
        mx.z = fmaxf(mx.z, v.z); mx.w = fmaxf(mx.w, v.w);
    }
    sS[sub][lane] = sum; sM[sub][lane] = mx;
    __syncthreads();
    if (sub == 0) {
        #pragma unroll
        for (int j = 1; j < 4; ++j) {
            float4 a = sS[j][lane], b = sM[j][lane];
            sum.x += a.x; sum.y += a.y; sum.z += a.z; sum.w += a.w;
            mx.x = fmaxf(mx.x, b.x); mx.y = fmaxf(mx.y, b.y);
            mx.z = fmaxf(mx.z, b.z); mx.w = fmaxf(mx.w, b.w);
        }
        int cnt = e - s;
        float inv = 1.f / fmaxf((float)cnt, 1.f);
        float4 o;
        o.x = sum.x * inv + mx.x; o.y = sum.y * inv + mx.y;
        o.z = sum.z * inv + mx.z; o.w = sum.w * inv + mx.w;
        *(float4*)&p[(size_t)g * HCDIM + c0] = o;
    }
}

// ============================ Head: logits + softmax ============================
__global__ void logits_kernel(const float* __restrict__ p, const float* __restrict__ Wout,
                              const float* __restrict__ bout, float* __restrict__ out)
{
    __shared__ float red[256];
    __shared__ float lg[NCLS];
    int g = blockIdx.x, t = threadIdx.x;
    float pv = p[g * HCDIM + t];
    for (int j = 0; j < NCLS; ++j) {
        red[t] = pv * Wout[t * NCLS + j];
        __syncthreads();
        for (int off = 128; off > 0; off >>= 1) {
            if (t < off) red[t] += red[t + off];
            __syncthreads();
        }
        if (t == 0) lg[j] = red[0] + bout[j];
        __syncthreads();
    }
    if (t == 0) {
        float mx = fmaxf(lg[0], fmaxf(lg[1], lg[2]));
        float e0 = __expf(lg[0] - mx), e1 = __expf(lg[1] - mx), e2 = __expf(lg[2] - mx);
        float inv = 1.f / (e0 + e1 + e2);
        out[g * NCLS + 0] = e0 * inv;
        out[g * NCLS + 1] = e1 * inv;
        out[g * NCLS + 2] = e2 * inv;
    }
}

// ============================ Orchestration ============================
extern "C" void kernel_launch(void* const* d_in, const int* in_sizes, int n_in,
                              void* d_out, int out_size, void* d_ws, size_t ws_size,
                              hipStream_t stream) {
    const float* x     = (const float*)d_in[0];
    const int*   ei    = (const int*)d_in[1];
    const int*   batch = (const int*)d_in[2];
    const float *Wl[3], *bl[3], *Wr[3], *br[3], *att[3], *bias[3];
    for (int li = 0; li < 3; ++li) {
        int b = 3 + li * 6;
        Wl[li]   = (const float*)d_in[b + 0];
        bl[li]   = (const float*)d_in[b + 1];
        Wr[li]   = (const float*)d_in[b + 2];
        br[li]   = (const float*)d_in[b + 3];
        att[li]  = (const float*)d_in[b + 4];
        bias[li] = (const float*)d_in[b + 5];
    }
    const float* Wout = (const float*)d_in[21];
    const float* bout = (const float*)d_in[22];
    float* out = (float*)d_out;

    size_t off = 0;
    char* wsb = (char*)d_ws;
    auto alloc = [&](size_t bytes) -> char* {
        char* ptr = wsb + off;
        off += (bytes + 255) & ~(size_t)255;
        return ptr;
    };
    // deg + startg + endg in one zero-init block (single memset)
    int* zblk    = (int*)alloc((N_NODES + 2 * NGRAPH) * sizeof(int));
    int* deg     = zblk;
    int* startg  = zblk + N_NODES;
    int* endg    = zblk + N_NODES + NGRAPH;
    int* rowptr  = (int*)alloc((N_NODES + 1) * sizeof(int));
    int* cursor  = (int*)alloc(N_NODES * sizeof(int));
    int* bsums   = (int*)alloc(256 * sizeof(int));
    int* colx    = (int*)alloc((size_t)(N_EDGES + N_NODES + 8) * sizeof(int));
    _Float16* Abuf = (_Float16*)alloc((size_t)MPAD * HCDIM * sizeof(_Float16));
    _Float16* Bt[3];
    for (int li = 0; li < 3; ++li) {
        int K = (li == 0) ? F_INPUT : HCDIM;
        Bt[li] = (_Float16*)alloc((size_t)512 * K * sizeof(_Float16));
    }
    unsigned char* xl8 = (unsigned char*)alloc((size_t)N_NODES * HCDIM);
    _Float16* xrh  = (_Float16*)alloc((size_t)N_NODES * HCDIM * sizeof(_Float16));
    _Float16* hbuf = (_Float16*)alloc((size_t)N_NODES * HCDIM * sizeof(_Float16));
    float* pbuf    = (float*)alloc((size_t)NGRAPH * HCDIM * sizeof(float));

    hipMemsetAsync(zblk, 0, (N_NODES + 2 * NGRAPH) * sizeof(int), stream);

    hist_boundary_kernel<<<HIST_NB + BND_NB, 256, 0, stream>>>(ei, deg, batch, startg, endg);
    block_scan_kernel<<<SCAN_NB, 256, 0, stream>>>(deg, rowptr, bsums);
    scan_bsums_kernel<<<1, 256, 0, stream>>>(bsums);
    add_off_kernel<<<SCAN_NB, 256, 0, stream>>>(rowptr, cursor, bsums);
    fill_kernel<<<(N_EDGES + N_NODES + 8 + 255) / 256, 256, 0, stream>>>(ei, cursor, colx);

    prep_kernel<<<PREP_NB, 256, 0, stream>>>(x, Abuf, Bt[0], Bt[1], Bt[2],
                                             Wl[0], Wr[0], Wl[1], Wr[1], Wl[2], Wr[2]);

    for (int li = 0; li < 3; ++li) {
        int K = (li == 0) ? F_INPUT : HCDIM;
        gemm_mfma<<<(MPAD / 128) * 4, 256, 0, stream>>>(
            Abuf, Bt[li], K, bl[li], br[li], xl8, xrh);
        if (li < 2) {
            gat_edge<<<N_NODES / 4, 256, 0, stream>>>(
                xl8, xrh, att[li], bias[li], rowptr, colx, nullptr, Abuf, 1);
        } else {
            gat_edge<<<N_NODES / 4, 256, 0, stream>>>(
                xl8, xrh, att[li], bias[li], rowptr, colx, hbuf, nullptr, 0);
        }
    }

    pool_kernel<<<NGRAPH, 256, 0, stream>>>(hbuf, startg, endg, pbuf);
    logits_kernel<<<NGRAPH, 256, 0, stream>>>(pbuf, Wout, bout, out);
}

// Round 12
// 513.514 us; speedup vs baseline: 1.2476x; 1.1085x over previous
//
#include <hip/hip_runtime.h>
#include <math.h>

#define N_NODES 50000
#define N_EDGES 600000
#define F_INPUT 128
#define HCDIM 256
#define NGRAPH 64
#define NCLS 3
#define MPAD 50048   // 391 * 128, GEMM M padded
#define SCAN_NB ((N_NODES + 255) / 256)   // 196
#define LOG2E 1.4426950408889634f
#define NPART 32     // pooling partitions per graph

// fused prep kernel block ranges
#define SPLITX_NB (MPAD * F_INPUT / 4 / 256)            // 6256
#define ZERO_NB   (((MPAD - N_NODES) * HCDIM / 4 + 255) / 256)  // 12
#define WPREP_NB  (512 * (F_INPUT + HCDIM + HCDIM) / 256)       // 1280
#define PREP_NB   (SPLITX_NB + ZERO_NB + WPREP_NB)
// fused hist+boundary ranges
#define HIST_NB   ((N_EDGES + N_NODES + 255) / 256)     // 2540
#define BND_NB    ((N_NODES + 255) / 256)               // 196

typedef float f32x4 __attribute__((ext_vector_type(4)));
typedef float f32x2 __attribute__((ext_vector_type(2)));
typedef _Float16 f16x8 __attribute__((ext_vector_type(8)));
typedef _Float16 f16x4 __attribute__((ext_vector_type(4)));
typedef _Float16 h2 __attribute__((ext_vector_type(2)));

__device__ __forceinline__ void gl_lds16(const void* g, void* l) {
    __builtin_amdgcn_global_load_lds(
        (const __attribute__((address_space(1))) unsigned int*)g,
        (__attribute__((address_space(3))) unsigned int*)l, 16, 0, 0);
}

__device__ __forceinline__ h2 bch2(unsigned int u) { return __builtin_bit_cast(h2, u); }
__device__ __forceinline__ h2 pk16(float a, float b) {
    return __builtin_bit_cast(h2, __builtin_amdgcn_cvt_pkrtz(a, b));
}

// packed leaky_relu(0.2): max(v,0) + 0.2*min(v,0)
__device__ __forceinline__ h2 lrelu2(h2 v) {
    const h2 z = {(_Float16)0.f, (_Float16)0.f};
    const h2 c = {(_Float16)0.2f, (_Float16)0.2f};
    h2 mx = __builtin_elementwise_max(v, z);
    h2 mn = __builtin_elementwise_min(v, z);
    return mx + mn * c;
}

// ============================ hist + boundary (fused) ============================
__global__ void hist_boundary_kernel(const int* __restrict__ ei, int* __restrict__ deg,
                                     const int* __restrict__ batch,
                                     int* __restrict__ startg, int* __restrict__ endg) {
    int b = blockIdx.x;
    if (b < HIST_NB) {
        int i = b * 256 + threadIdx.x;
        int total = N_EDGES + N_NODES;
        if (i >= total) return;
        int d = (i < N_EDGES) ? ei[N_EDGES + i] : (i - N_EDGES);
        atomicAdd(&deg[d], 1);
    } else {
        int i = (b - HIST_NB) * 256 + threadIdx.x;
        if (i >= N_NODES) return;
        int g = batch[i];
        if (i == 0 || batch[i - 1] != g) startg[g] = i;
        if (i == N_NODES - 1 || batch[i + 1] != g) endg[g] = i + 1;
    }
}

// ============================ CSR scan ============================
__global__ void block_scan_kernel(const int* __restrict__ deg, int* __restrict__ rowptr,
                                  int* __restrict__ bsums) {
    __shared__ int wt[4];
    int b = blockIdx.x, t = threadIdx.x, lane = t & 63, wid = t >> 6;
    int i = b * 256 + t;
    int v = (i < N_NODES) ? deg[i] : 0;
    int x = v;
    #pragma unroll
    for (int off = 1; off < 64; off <<= 1) {
        int y = __shfl_up(x, off, 64);
        if (lane >= off) x += y;
    }
    if (lane == 63) wt[wid] = x;
    __syncthreads();
    if (t == 0) {
        int s = 0;
        #pragma unroll
        for (int j = 0; j < 4; ++j) { int tv = wt[j]; wt[j] = s; s += tv; }
        bsums[b] = s;
    }
    __syncthreads();
    if (i < N_NODES) rowptr[i] = wt[wid] + x - v;
}

__global__ void scan_bsums_kernel(int* __restrict__ bsums) {
    __shared__ int wt[4];
    int t = threadIdx.x, lane = t & 63, wid = t >> 6;
    int v = (t < SCAN_NB) ? bsums[t] : 0;
    int x = v;
    #pragma unroll
    for (int off = 1; off < 64; off <<= 1) {
        int y = __shfl_up(x, off, 64);
        if (lane >= off) x += y;
    }
    if (lane == 63) wt[wid] = x;
    __syncthreads();
    if (t == 0) {
        int s = 0;
        #pragma unroll
        for (int j = 0; j < 4; ++j) { int tv = wt[j]; wt[j] = s; s += tv; }
    }
    __syncthreads();
    if (t < SCAN_NB) bsums[t] = wt[wid] + x - v;
}

__global__ void add_off_kernel(int* __restrict__ rowptr, int* __restrict__ cursor,
                               const int* __restrict__ bsums) {
    int i = blockIdx.x * 256 + threadIdx.x;
    if (i < N_NODES) {
        int r = rowptr[i] + bsums[blockIdx.x];
        rowptr[i] = r;
        cursor[i] = r;
    }
    if (i == 0) rowptr[N_NODES] = N_EDGES + N_NODES;
}

// colx stores BYTE offsets into the fp8 xl matrix: s * HCDIM (256 B rows).
// Entries [total, total+8) are zero padding so the edge loop needs no prefetch clamps.
__global__ void fill_kernel(const int* __restrict__ ei, int* __restrict__ cursor,
                            int* __restrict__ colx) {
    int i = blockIdx.x * 256 + threadIdx.x;
    int total = N_EDGES + N_NODES;
    if (i >= total + 8) return;
    if (i >= total) { colx[i] = 0; return; }
    int s, d;
    if (i < N_EDGES) { s = ei[i]; d = ei[N_EDGES + i]; }
    else             { s = i - N_EDGES; d = s; }
    int pos = atomicAdd(&cursor[d], 1);
    colx[pos] = s * HCDIM;
}

// ============================ Fused prep: x->fp16, pad zero, W->fp16 n-major ============================
__global__ void prep_kernel(const float* __restrict__ x, _Float16* __restrict__ A,
                            _Float16* __restrict__ Bt0, _Float16* __restrict__ Bt1,
                            _Float16* __restrict__ Bt2,
                            const float* __restrict__ Wl0, const float* __restrict__ Wr0,
                            const float* __restrict__ Wl1, const float* __restrict__ Wr1,
                            const float* __restrict__ Wl2, const float* __restrict__ Wr2) {
    int b = blockIdx.x;
    if (b < SPLITX_NB) {
        int base = (b * 256 + threadIdx.x) * 4;
        int row = base >> 7;
        float4 v = make_float4(0.f, 0.f, 0.f, 0.f);
        if (row < N_NODES) v = *(const float4*)&x[base];
        f16x4 o;
        o.x = (_Float16)v.x; o.y = (_Float16)v.y; o.z = (_Float16)v.z; o.w = (_Float16)v.w;
        *(f16x4*)&A[base] = o;
    } else if (b < SPLITX_NB + ZERO_NB) {
        int i = ((b - SPLITX_NB) * 256 + threadIdx.x) * 4;
        if (i < (MPAD - N_NODES) * HCDIM) {
            f16x4 z = {(_Float16)0.f, (_Float16)0.f, (_Float16)0.f, (_Float16)0.f};
            *(f16x4*)&A[(size_t)N_NODES * HCDIM + i] = z;
        }
    } else {
        int t = (b - SPLITX_NB - ZERO_NB) * 256 + threadIdx.x;
        const float* Wl; const float* Wr; _Float16* Bt; int K;
        if (t < 512 * F_INPUT)            { Wl = Wl0; Wr = Wr0; Bt = Bt0; K = F_INPUT; }
        else if (t < 512 * (F_INPUT + HCDIM)) { t -= 512 * F_INPUT; Wl = Wl1; Wr = Wr1; Bt = Bt1; K = HCDIM; }
        else                              { t -= 512 * (F_INPUT + HCDIM); Wl = Wl2; Wr = Wr2; Bt = Bt2; K = HCDIM; }
        int n = t & 511, k = t >> 9;
        float w = (n < 256) ? Wl[k * 256 + n] : Wr[k * 256 + (n - 256)];
        Bt[n * K + k] = (_Float16)w;
    }
}

// ============================ fp16 MFMA GEMM, BK=64 ============================
__global__ __launch_bounds__(256) void gemm_mfma(
    const _Float16* __restrict__ A, const _Float16* __restrict__ B,
    int K,
    const float* __restrict__ bl, const float* __restrict__ br,
    unsigned char* __restrict__ xl8, _Float16* __restrict__ xrh)
{
    __shared__ _Float16 sA[128 * 64], sB[128 * 64];
    int tid = threadIdx.x;
    int lane = tid & 63, wave = tid >> 6;
    int wm = wave >> 1, wn = wave & 1;
    int bx = blockIdx.x >> 2, by = blockIdx.x & 3;
    int row0 = bx * 128;
    int n0 = by * 128;
    int quad = lane >> 4, l16 = lane & 15;

    f32x4 acc[4][4];
    #pragma unroll
    for (int i = 0; i < 4; ++i)
        #pragma unroll
        for (int j = 0; j < 4; ++j)
            acc[i][j] = (f32x4){0.f, 0.f, 0.f, 0.f};

    for (int k0 = 0; k0 < K; k0 += 64) {
        __syncthreads();
        #pragma unroll
        for (int pass = 0; pass < 4; ++pass) {
            int c = tid + pass * 256;           // chunk 0..1023 (16 B each)
            int r = c >> 3;                     // tile row
            int pl = c & 7;                     // physical k-chunk in LDS row
            int pg = pl ^ (r & 7);              // global k-chunk (swizzled)
            size_t ga = (size_t)(row0 + r) * K + k0 + pg * 8;
            size_t gb = (size_t)(n0 + r) * K + k0 + pg * 8;
            gl_lds16(A + ga, sA + c * 8);
            gl_lds16(B + gb, sB + c * 8);
        }
        __syncthreads();

        #pragma unroll
        for (int kk = 0; kk < 2; ++kk) {
            f16x8 fa[4], fb[4];
            #pragma unroll
            for (int i = 0; i < 4; ++i) {
                int rr = wm * 64 + i * 16 + l16;
                int ca = (kk * 4 + quad) ^ (rr & 7);
                fa[i] = *(const f16x8*)&sA[rr * 64 + ca * 8];
                int nn = wn * 64 + i * 16 + l16;
                int cb = (kk * 4 + quad) ^ (nn & 7);
                fb[i] = *(const f16x8*)&sB[nn * 64 + cb * 8];
            }
            #pragma unroll
            for (int i = 0; i < 4; ++i)
                #pragma unroll
                for (int j = 0; j < 4; ++j)
                    acc[i][j] = __builtin_amdgcn_mfma_f32_16x16x32_f16(fa[i], fb[j], acc[i][j], 0, 0, 0);
        }
    }

    if (by < 2) {
        int cb0 = by * 128;
        #pragma unroll
        for (int j = 0; j < 4; ++j) {
            int col = cb0 + wn * 64 + j * 16 + l16;
            float bj = bl[col];
            #pragma unroll
            for (int i = 0; i < 4; ++i) {
                int rbase = row0 + wm * 64 + i * 16 + quad * 4;
                #pragma unroll
                for (int r = 0; r < 4; ++r) {
                    int row = rbase + r;
                    if (row < N_NODES) {
                        float v = acc[i][j][r] + bj;
                        int pk = __builtin_amdgcn_cvt_pk_fp8_f32(v, v, 0, false);
                        xl8[(size_t)row * HCDIM + col] = (unsigned char)pk;
                    }
                }
            }
        }
    } else {
        int cb0 = (by - 2) * 128;
        #pragma unroll
        for (int j = 0; j < 4; ++j) {
            int col = cb0 + wn * 64 + j * 16 + l16;
            float bj = br[col];
            #pragma unroll
            for (int i = 0; i < 4; ++i) {
                int rbase = row0 + wm * 64 + i * 16 + quad * 4;
                #pragma unroll
                for (int r = 0; r < 4; ++r) {
                    int row = rbase + r;
                    if (row < N_NODES)
                        xrh[(size_t)row * HCDIM + col] = (_Float16)(acc[i][j][r] + bj);
                }
            }
        }
    }
}

// ============================ Edge phase: fp8 gather, no-max exp2 softmax, lean 4-edge unroll ============================
__global__ __launch_bounds__(256) void gat_edge(
    const unsigned char* __restrict__ xl8, const _Float16* __restrict__ xrh,
    const float* __restrict__ att, const float* __restrict__ bias,
    const int* __restrict__ rowptr, const int* __restrict__ colx,
    _Float16* __restrict__ outh, _Float16* __restrict__ onext, int mode)
{
    int wave = threadIdx.x >> 6;
    int lane = threadIdx.x & 63;
    int node = blockIdx.x * 4 + wave;
    if (node >= N_NODES) return;
    int lb8  = lane * 4;                     // byte offset within fp8 row
    int lb16 = lane * 8;                     // byte offset within fp16 row
    const char* xlb = (const char*)xl8;

    uint2 xrr = *(const uint2*)((const char*)xrh + (size_t)node * (HCDIM * 2) + lb16);
    h2 xra = bch2(xrr.x), xrb = bch2(xrr.y);
    float4 at4 = *(const float4*)&att[lane * 4];
    // pre-scale attention by log2(e): scores come out ready for exp2
    h2 ata = {(_Float16)(at4.x * LOG2E), (_Float16)(at4.y * LOG2E)};
    h2 atb = {(_Float16)(at4.z * LOG2E), (_Float16)(at4.w * LOG2E)};

    int e0 = rowptr[node], e1 = rowptr[node + 1];
    float denom = 0.f;
    float4 acc = make_float4(0.f, 0.f, 0.f, 0.f);

    unsigned int d[4];
    #pragma unroll
    for (int k = 0; k < 4; ++k)
        d[k] = *(const unsigned int*)(xlb + (size_t)(unsigned)colx[e0 + k] + lb8);

    for (int e = e0; e < e1; e += 4) {
        unsigned int nd[4];
        #pragma unroll
        for (int k = 0; k < 4; ++k)
            nd[k] = *(const unsigned int*)(xlb + (size_t)(unsigned)colx[e + 4 + k] + lb8);

        f32x2 lo[4], hi[4];
        float p[4];
        #pragma unroll
        for (int k = 0; k < 4; ++k) {
            lo[k] = __builtin_amdgcn_cvt_pk_f32_fp8(d[k], false);
            hi[k] = __builtin_amdgcn_cvt_pk_f32_fp8(d[k], true);
            h2 a = pk16(lo[k].x, lo[k].y);
            h2 b = pk16(hi[k].x, hi[k].y);
            h2 la = lrelu2(a + xra);
            h2 lbv = lrelu2(b + xrb);
            float pp = __builtin_amdgcn_fdot2(la, ata, 0.f, false);
            p[k] = __builtin_amdgcn_fdot2(lbv, atb, pp, false);
        }
        #pragma unroll
        for (int off = 1; off <= 8; off <<= 1) {
            #pragma unroll
            for (int k = 0; k < 4; ++k) p[k] += __shfl_xor(p[k], off, 64);
        }
        float w[4];
        #pragma unroll
        for (int k = 0; k < 4; ++k)
            w[k] = (e + k < e1) ? exp2f(p[k]) : 0.f;

        denom += (w[0] + w[1]) + (w[2] + w[3]);
        acc.x += w[0] * lo[0].x + w[1] * lo[1].x + w[2] * lo[2].x + w[3] * lo[3].x;
        acc.y += w[0] * lo[0].y + w[1] * lo[1].y + w[2] * lo[2].y + w[3] * lo[3].y;
        acc.z += w[0] * hi[0].x + w[1] * hi[1].x + w[2] * hi[2].x + w[3] * hi[3].x;
        acc.w += w[0] * hi[0].y + w[1] * hi[1].y + w[2] * hi[2].y + w[3] * hi[3].y;
        d[0] = nd[0]; d[1] = nd[1]; d[2] = nd[2]; d[3] = nd[3];
    }

    float inv = 1.f / denom;
    float4 b4 = *(const float4*)&bias[lane * 4];
    float ox = acc.x * inv + b4.x;
    float oy = acc.y * inv + b4.y;
    float oz = acc.z * inv + b4.z;
    float ow = acc.w * inv + b4.w;
    if (mode == 0) {
        f16x4 h;
        h.x = (_Float16)ox; h.y = (_Float16)oy;
        h.z = (_Float16)oz; h.w = (_Float16)ow;
        *(f16x4*)((char*)outh + (size_t)node * (HCDIM * 2) + lb16) = h;
    } else {
        f16x4 h;
        h.x = (_Float16)fmaxf(ox, 0.f); h.y = (_Float16)fmaxf(oy, 0.f);
        h.z = (_Float16)fmaxf(oz, 0.f); h.w = (_Float16)fmaxf(ow, 0.f);
        *(f16x4*)((char*)onext + (size_t)node * (HCDIM * 2) + lb16) = h;
    }
}

// ============================ Two-stage pooling ============================
// Stage 1: NGRAPH*NPART blocks; each reduces a strided row-slice of its graph.
__global__ __launch_bounds__(256) void pool_partial(
    const _Float16* __restrict__ h, const int* __restrict__ startg,
    const int* __restrict__ endg, float* __restrict__ sumP, float* __restrict__ maxP)
{
    __shared__ float4 sS[4][64];
    __shared__ float4 sM[4][64];
    int g = blockIdx.x >> 5, part = blockIdx.x & (NPART - 1);
    int lane = threadIdx.x & 63;
    int sub = threadIdx.x >> 6;
    int c0 = lane * 4;
    int s = startg[g], e = endg[g];
    float4 sum = make_float4(0.f, 0.f, 0.f, 0.f);
    float4 mx = make_float4(-INFINITY, -INFINITY, -INFINITY, -INFINITY);
    for (int i = s + part * 4 + sub; i < e; i += NPART * 4) {
        uint2 u = *(const uint2*)&h[(size_t)i * HCDIM + c0];
        h2 a = bch2(u.x), b = bch2(u.y);
        float4 v = make_float4((float)a.x, (float)a.y, (float)b.x, (float)b.y);
        sum.x += v.x; sum.y += v.y; sum.z += v.z; sum.w += v.w;
        mx.x = fmaxf(mx.x, v.x); mx.y = fmaxf(mx.y, v.y);
        mx.z = fmaxf(mx.z, v.z); mx.w = fmaxf(mx.w, v.w);
    }
    sS[sub][lane] = sum; sM[sub][lane] = mx;
    __syncthreads();
    if (sub == 0) {
        #pragma unroll
        for (int j = 1; j < 4; ++j) {
            float4 a = sS[j][lane], b = sM[j][lane];
            sum.x += a.x; sum.y += a.y; sum.z += a.z; sum.w += a.w;
            mx.x = fmaxf(mx.x, b.x); mx.y = fmaxf(mx.y, b.y);
            mx.z = fmaxf(mx.z, b.z); mx.w = fmaxf(mx.w, b.w);
        }
        size_t o = (size_t)blockIdx.x * HCDIM + c0;
        *(float4*)&sumP[o] = sum;
        *(float4*)&maxP[o] = mx;
    }
}

// Stage 2: NGRAPH blocks; thread c combines NPART partials for channel c, applies mean+max.
__global__ __launch_bounds__(256) void pool_final(
    const float* __restrict__ sumP, const float* __restrict__ maxP,
    const int* __restrict__ startg, const int* __restrict__ endg,
    float* __restrict__ p)
{
    int g = blockIdx.x, c = threadIdx.x;
    float s = 0.f, m = -INFINITY;
    #pragma unroll 8
    for (int part = 0; part < NPART; ++part) {
        size_t o = (size_t)(g * NPART + part) * HCDIM + c;
        s += sumP[o];
        m = fmaxf(m, maxP[o]);
    }
    int cnt = endg[g] - startg[g];
    float inv = 1.f / fmaxf((float)cnt, 1.f);
    p[(size_t)g * HCDIM + c] = s * inv + m;
}

// ============================ Head: logits + softmax ============================
__global__ void logits_kernel(const float* __restrict__ p, const float* __restrict__ Wout,
                              const float* __restrict__ bout, float* __restrict__ out)
{
    __shared__ float red[256];
    __shared__ float lg[NCLS];
    int g = blockIdx.x, t = threadIdx.x;
    float pv = p[g * HCDIM + t];
    for (int j = 0; j < NCLS; ++j) {
        red[t] = pv * Wout[t * NCLS + j];
        __syncthreads();
        for (int off = 128; off > 0; off >>= 1) {
            if (t < off) red[t] += red[t + off];
            __syncthreads();
        }
        if (t == 0) lg[j] = red[0] + bout[j];
        __syncthreads();
    }
    if (t == 0) {
        float mx = fmaxf(lg[0], fmaxf(lg[1], lg[2]));
        float e0 = __expf(lg[0] - mx), e1 = __expf(lg[1] - mx), e2 = __expf(lg[2] - mx);
        float inv = 1.f / (e0 + e1 + e2);
        out[g * NCLS + 0] = e0 * inv;
        out[g * NCLS + 1] = e1 * inv;
        out[g * NCLS + 2] = e2 * inv;
    }
}

// ============================ Orchestration ============================
extern "C" void kernel_launch(void* const* d_in, const int* in_sizes, int n_in,
                              void* d_out, int out_size, void* d_ws, size_t ws_size,
                              hipStream_t stream) {
    const float* x     = (const float*)d_in[0];
    const int*   ei    = (const int*)d_in[1];
    const int*   batch = (const int*)d_in[2];
    const float *Wl[3], *bl[3], *Wr[3], *br[3], *att[3], *bias[3];
    for (int li = 0; li < 3; ++li) {
        int b = 3 + li * 6;
        Wl[li]   = (const float*)d_in[b + 0];
        bl[li]   = (const float*)d_in[b + 1];
        Wr[li]   = (const float*)d_in[b + 2];
        br[li]   = (const float*)d_in[b + 3];
        att[li]  = (const float*)d_in[b + 4];
        bias[li] = (const float*)d_in[b + 5];
    }
    const float* Wout = (const float*)d_in[21];
    const float* bout = (const float*)d_in[22];
    float* out = (float*)d_out;

    size_t off = 0;
    char* wsb = (char*)d_ws;
    auto alloc = [&](size_t bytes) -> char* {
        char* ptr = wsb + off;
        off += (bytes + 255) & ~(size_t)255;
        return ptr;
    };
    // deg + startg + endg in one zero-init block (single memset)
    int* zblk    = (int*)alloc((N_NODES + 2 * NGRAPH) * sizeof(int));
    int* deg     = zblk;
    int* startg  = zblk + N_NODES;
    int* endg    = zblk + N_NODES + NGRAPH;
    int* rowptr  = (int*)alloc((N_NODES + 1) * sizeof(int));
    int* cursor  = (int*)alloc(N_NODES * sizeof(int));
    int* bsums   = (int*)alloc(256 * sizeof(int));
    int* colx    = (int*)alloc((size_t)(N_EDGES + N_NODES + 8) * sizeof(int));
    _Float16* Abuf = (_Float16*)alloc((size_t)MPAD * HCDIM * sizeof(_Float16));
    _Float16* Bt[3];
    for (int li = 0; li < 3; ++li) {
        int K = (li == 0) ? F_INPUT : HCDIM;
        Bt[li] = (_Float16*)alloc((size_t)512 * K * sizeof(_Float16));
    }
    unsigned char* xl8 = (unsigned char*)alloc((size_t)N_NODES * HCDIM);
    _Float16* xrh  = (_Float16*)alloc((size_t)N_NODES * HCDIM * sizeof(_Float16));
    _Float16* hbuf = (_Float16*)alloc((size_t)N_NODES * HCDIM * sizeof(_Float16));
    float* sumP    = (float*)alloc((size_t)NGRAPH * NPART * HCDIM * sizeof(float));
    float* maxP    = (float*)alloc((size_t)NGRAPH * NPART * HCDIM * sizeof(float));
    float* pbuf    = (float*)alloc((size_t)NGRAPH * HCDIM * sizeof(float));

    hipMemsetAsync(zblk, 0, (N_NODES + 2 * NGRAPH) * sizeof(int), stream);

    hist_boundary_kernel<<<HIST_NB + BND_NB, 256, 0, stream>>>(ei, deg, batch, startg, endg);
    block_scan_kernel<<<SCAN_NB, 256, 0, stream>>>(deg, rowptr, bsums);
    scan_bsums_kernel<<<1, 256, 0, stream>>>(bsums);
    add_off_kernel<<<SCAN_NB, 256, 0, stream>>>(rowptr, cursor, bsums);
    fill_kernel<<<(N_EDGES + N_NODES + 8 + 255) / 256, 256, 0, stream>>>(ei, cursor, colx);

    prep_kernel<<<PREP_NB, 256, 0, stream>>>(x, Abuf, Bt[0], Bt[1], Bt[2],
                                             Wl[0], Wr[0], Wl[1], Wr[1], Wl[2], Wr[2]);

    for (int li = 0; li < 3; ++li) {
        int K = (li == 0) ? F_INPUT : HCDIM;
        gemm_mfma<<<(MPAD / 128) * 4, 256, 0, stream>>>(
            Abuf, Bt[li], K, bl[li], br[li], xl8, xrh);
        if (li < 2) {
            gat_edge<<<N_NODES / 4, 256, 0, stream>>>(
                xl8, xrh, att[li], bias[li], rowptr, colx, nullptr, Abuf, 1);
        } else {
            gat_edge<<<N_NODES / 4, 256, 0, stream>>>(
                xl8, xrh, att[li], bias[li], rowptr, colx, hbuf, nullptr, 0);
        }
    }

    pool_partial<<<NGRAPH * NPART, 256, 0, stream>>>(hbuf, startg, endg, sumP, maxP);
    pool_final<<<NGRAPH, 256, 0, stream>>>(sumP, maxP, startg, endg, pbuf);
    logits_kernel<<<NGRAPH, 256, 0, stream>>>(pbuf, Wout, bout, out);
}

// Round 13
// 470.112 us; speedup vs baseline: 1.3628x; 1.0923x over previous
//
#include <hip/hip_runtime.h>
#include <math.h>

#define N_NODES 50000
#define N_EDGES 600000
#define F_INPUT 128
#define HCDIM 256
#define NGRAPH 64
#define NCLS 3
#define MPAD 50048   // 782 * 64, GEMM M padded
#define SCAN_NB ((N_NODES + 255) / 256)   // 196
#define LOG2E 1.4426950408889634f
#define NPART 32     // pooling partitions per graph

// fused prep kernel block ranges
#define SPLITX_NB (MPAD * F_INPUT / 4 / 256)            // 6256
#define ZERO_NB   (((MPAD - N_NODES) * HCDIM / 4 + 255) / 256)  // 12
#define WPREP_NB  (512 * (F_INPUT + HCDIM + HCDIM) / 256)       // 1280
#define PREP_NB   (SPLITX_NB + ZERO_NB + WPREP_NB)
// fused hist+boundary ranges
#define HIST_NB   ((N_EDGES + N_NODES + 255) / 256)     // 2540
#define BND_NB    ((N_NODES + 255) / 256)               // 196

typedef float f32x4 __attribute__((ext_vector_type(4)));
typedef float f32x2 __attribute__((ext_vector_type(2)));
typedef _Float16 f16x8 __attribute__((ext_vector_type(8)));
typedef _Float16 f16x4 __attribute__((ext_vector_type(4)));
typedef _Float16 h2 __attribute__((ext_vector_type(2)));

__device__ __forceinline__ void gl_lds16(const void* g, void* l) {
    __builtin_amdgcn_global_load_lds(
        (const __attribute__((address_space(1))) unsigned int*)g,
        (__attribute__((address_space(3))) unsigned int*)l, 16, 0, 0);
}

__device__ __forceinline__ h2 bch2(unsigned int u) { return __builtin_bit_cast(h2, u); }
__device__ __forceinline__ h2 pk16(float a, float b) {
    return __builtin_bit_cast(h2, __builtin_amdgcn_cvt_pkrtz(a, b));
}

// packed leaky_relu(0.2): max(v,0) + 0.2*min(v,0)
__device__ __forceinline__ h2 lrelu2(h2 v) {
    const h2 z = {(_Float16)0.f, (_Float16)0.f};
    const h2 c = {(_Float16)0.2f, (_Float16)0.2f};
    h2 mx = __builtin_elementwise_max(v, z);
    h2 mn = __builtin_elementwise_min(v, z);
    return mx + mn * c;
}

// ============================ hist + boundary (fused) ============================
__global__ void hist_boundary_kernel(const int* __restrict__ ei, int* __restrict__ deg,
                                     const int* __restrict__ batch,
                                     int* __restrict__ startg, int* __restrict__ endg) {
    int b = blockIdx.x;
    if (b < HIST_NB) {
        int i = b * 256 + threadIdx.x;
        int total = N_EDGES + N_NODES;
        if (i >= total) return;
        int d = (i < N_EDGES) ? ei[N_EDGES + i] : (i - N_EDGES);
        atomicAdd(&deg[d], 1);
    } else {
        int i = (b - HIST_NB) * 256 + threadIdx.x;
        if (i >= N_NODES) return;
        int g = batch[i];
        if (i == 0 || batch[i - 1] != g) startg[g] = i;
        if (i == N_NODES - 1 || batch[i + 1] != g) endg[g] = i + 1;
    }
}

// ============================ CSR scan ============================
__global__ void block_scan_kernel(const int* __restrict__ deg, int* __restrict__ rowptr,
                                  int* __restrict__ bsums) {
    __shared__ int wt[4];
    int b = blockIdx.x, t = threadIdx.x, lane = t & 63, wid = t >> 6;
    int i = b * 256 + t;
    int v = (i < N_NODES) ? deg[i] : 0;
    int x = v;
    #pragma unroll
    for (int off = 1; off < 64; off <<= 1) {
        int y = __shfl_up(x, off, 64);
        if (lane >= off) x += y;
    }
    if (lane == 63) wt[wid] = x;
    __syncthreads();
    if (t == 0) {
        int s = 0;
        #pragma unroll
        for (int j = 0; j < 4; ++j) { int tv = wt[j]; wt[j] = s; s += tv; }
        bsums[b] = s;
    }
    __syncthreads();
    if (i < N_NODES) rowptr[i] = wt[wid] + x - v;
}

__global__ void scan_bsums_kernel(int* __restrict__ bsums) {
    __shared__ int wt[4];
    int t = threadIdx.x, lane = t & 63, wid = t >> 6;
    int v = (t < SCAN_NB) ? bsums[t] : 0;
    int x = v;
    #pragma unroll
    for (int off = 1; off < 64; off <<= 1) {
        int y = __shfl_up(x, off, 64);
        if (lane >= off) x += y;
    }
    if (lane == 63) wt[wid] = x;
    __syncthreads();
    if (t == 0) {
        int s = 0;
        #pragma unroll
        for (int j = 0; j < 4; ++j) { int tv = wt[j]; wt[j] = s; s += tv; }
    }
    __syncthreads();
    if (t < SCAN_NB) bsums[t] = wt[wid] + x - v;
}

__global__ void add_off_kernel(int* __restrict__ rowptr, int* __restrict__ cursor,
                               const int* __restrict__ bsums) {
    int i = blockIdx.x * 256 + threadIdx.x;
    if (i < N_NODES) {
        int r = rowptr[i] + bsums[blockIdx.x];
        rowptr[i] = r;
        cursor[i] = r;
    }
    if (i == 0) rowptr[N_NODES] = N_EDGES + N_NODES;
}

// colx stores BYTE offsets into the fp8 xl matrix: s * HCDIM (256 B rows).
// Entries [total, total+8) are zero padding so the edge loop needs no prefetch clamps.
__global__ void fill_kernel(const int* __restrict__ ei, int* __restrict__ cursor,
                            int* __restrict__ colx) {
    int i = blockIdx.x * 256 + threadIdx.x;
    int total = N_EDGES + N_NODES;
    if (i >= total + 8) return;
    if (i >= total) { colx[i] = 0; return; }
    int s, d;
    if (i < N_EDGES) { s = ei[i]; d = ei[N_EDGES + i]; }
    else             { s = i - N_EDGES; d = s; }
    int pos = atomicAdd(&cursor[d], 1);
    colx[pos] = s * HCDIM;
}

// ============================ Fused prep: x->fp16, pad zero, W->fp16 n-major ============================
__global__ void prep_kernel(const float* __restrict__ x, _Float16* __restrict__ A,
                            _Float16* __restrict__ Bt0, _Float16* __restrict__ Bt1,
                            _Float16* __restrict__ Bt2,
                            const float* __restrict__ Wl0, const float* __restrict__ Wr0,
                            const float* __restrict__ Wl1, const float* __restrict__ Wr1,
                            const float* __restrict__ Wl2, const float* __restrict__ Wr2) {
    int b = blockIdx.x;
    if (b < SPLITX_NB) {
        int base = (b * 256 + threadIdx.x) * 4;
        int row = base >> 7;
        float4 v = make_float4(0.f, 0.f, 0.f, 0.f);
        if (row < N_NODES) v = *(const float4*)&x[base];
        f16x4 o;
        o.x = (_Float16)v.x; o.y = (_Float16)v.y; o.z = (_Float16)v.z; o.w = (_Float16)v.w;
        *(f16x4*)&A[base] = o;
    } else if (b < SPLITX_NB + ZERO_NB) {
        int i = ((b - SPLITX_NB) * 256 + threadIdx.x) * 4;
        if (i < (MPAD - N_NODES) * HCDIM) {
            f16x4 z = {(_Float16)0.f, (_Float16)0.f, (_Float16)0.f, (_Float16)0.f};
            *(f16x4*)&A[(size_t)N_NODES * HCDIM + i] = z;
        }
    } else {
        int t = (b - SPLITX_NB - ZERO_NB) * 256 + threadIdx.x;
        const float* Wl; const float* Wr; _Float16* Bt; int K;
        if (t < 512 * F_INPUT)            { Wl = Wl0; Wr = Wr0; Bt = Bt0; K = F_INPUT; }
        else if (t < 512 * (F_INPUT + HCDIM)) { t -= 512 * F_INPUT; Wl = Wl1; Wr = Wr1; Bt = Bt1; K = HCDIM; }
        else                              { t -= 512 * (F_INPUT + HCDIM); Wl = Wl2; Wr = Wr2; Bt = Bt2; K = HCDIM; }
        int n = t & 511, k = t >> 9;
        float w = (n < 256) ? Wl[k * 256 + n] : Wr[k * 256 + (n - 256)];
        Bt[n * K + k] = (_Float16)w;
    }
}

// ============================ fp16 MFMA GEMM, 64x128 tile, BK=64 ============================
// Small tile for occupancy: 24 KB LDS -> 6 blocks/CU, 32 acc VGPRs/wave, grid 3128 blocks.
// TLP hides the staging latency that stalled the 128x128 version (15% occupancy, 8% MfmaUtil).
// 4 waves as 2x2: wave rows wm*32 (2 tiles), cols wn*64 (4 tiles).
__global__ __launch_bounds__(256) void gemm_mfma(
    const _Float16* __restrict__ A, const _Float16* __restrict__ B,
    int K,
    const float* __restrict__ bl, const float* __restrict__ br,
    unsigned char* __restrict__ xl8, _Float16* __restrict__ xrh)
{
    __shared__ _Float16 sA[64 * 64], sB[128 * 64];
    int tid = threadIdx.x;
    int lane = tid & 63, wave = tid >> 6;
    int wm = wave >> 1, wn = wave & 1;
    int bx = blockIdx.x >> 2, by = blockIdx.x & 3;
    int row0 = bx * 64;
    int n0 = by * 128;
    int quad = lane >> 4, l16 = lane & 15;

    f32x4 acc[2][4];
    #pragma unroll
    for (int i = 0; i < 2; ++i)
        #pragma unroll
        for (int j = 0; j < 4; ++j)
            acc[i][j] = (f32x4){0.f, 0.f, 0.f, 0.f};

    for (int k0 = 0; k0 < K; k0 += 64) {
        __syncthreads();
        // A: 512 chunks (64 rows x 8), B: 1024 chunks (128 rows x 8); 6 per thread
        #pragma unroll
        for (int pass = 0; pass < 2; ++pass) {
            int c = tid + pass * 256;           // A chunk 0..511
            int r = c >> 3;
            int pl = c & 7;
            int pg = pl ^ (r & 7);
            size_t ga = (size_t)(row0 + r) * K + k0 + pg * 8;
            gl_lds16(A + ga, sA + c * 8);
        }
        #pragma unroll
        for (int pass = 0; pass < 4; ++pass) {
            int c = tid + pass * 256;           // B chunk 0..1023
            int r = c >> 3;
            int pl = c & 7;
            int pg = pl ^ (r & 7);
            size_t gb = (size_t)(n0 + r) * K + k0 + pg * 8;
            gl_lds16(B + gb, sB + c * 8);
        }
        __syncthreads();

        #pragma unroll
        for (int kk = 0; kk < 2; ++kk) {
            f16x8 fa[2], fb[4];
            #pragma unroll
            for (int i = 0; i < 2; ++i) {
                int rr = wm * 32 + i * 16 + l16;
                int ca = (kk * 4 + quad) ^ (rr & 7);
                fa[i] = *(const f16x8*)&sA[rr * 64 + ca * 8];
            }
            #pragma unroll
            for (int j = 0; j < 4; ++j) {
                int nn = wn * 64 + j * 16 + l16;
                int cb = (kk * 4 + quad) ^ (nn & 7);
                fb[j] = *(const f16x8*)&sB[nn * 64 + cb * 8];
            }
            #pragma unroll
            for (int i = 0; i < 2; ++i)
                #pragma unroll
                for (int j = 0; j < 4; ++j)
                    acc[i][j] = __builtin_amdgcn_mfma_f32_16x16x32_f16(fa[i], fb[j], acc[i][j], 0, 0, 0);
        }
    }

    if (by < 2) {
        int cb0 = by * 128;
        #pragma unroll
        for (int j = 0; j < 4; ++j) {
            int col = cb0 + wn * 64 + j * 16 + l16;
            float bj = bl[col];
            #pragma unroll
            for (int i = 0; i < 2; ++i) {
                int rbase = row0 + wm * 32 + i * 16 + quad * 4;
                #pragma unroll
                for (int r = 0; r < 4; ++r) {
                    int row = rbase + r;
                    if (row < N_NODES) {
                        float v = acc[i][j][r] + bj;
                        int pk = __builtin_amdgcn_cvt_pk_fp8_f32(v, v, 0, false);
                        xl8[(size_t)row * HCDIM + col] = (unsigned char)pk;
                    }
                }
            }
        }
    } else {
        int cb0 = (by - 2) * 128;
        #pragma unroll
        for (int j = 0; j < 4; ++j) {
            int col = cb0 + wn * 64 + j * 16 + l16;
            float bj = br[col];
            #pragma unroll
            for (int i = 0; i < 2; ++i) {
                int rbase = row0 + wm * 32 + i * 16 + quad * 4;
                #pragma unroll
                for (int r = 0; r < 4; ++r) {
                    int row = rbase + r;
                    if (row < N_NODES)
                        xrh[(size_t)row * HCDIM + col] = (_Float16)(acc[i][j][r] + bj);
                }
            }
        }
    }
}

// ============================ Edge phase: fp8 gather, no-max exp2 softmax, lean 4-edge unroll ============================
__global__ __launch_bounds__(256) void gat_edge(
    const unsigned char* __restrict__ xl8, const _Float16* __restrict__ xrh,
    const float* __restrict__ att, const float* __restrict__ bias,
    const int* __restrict__ rowptr, const int* __restrict__ colx,
    _Float16* __restrict__ outh, _Float16* __restrict__ onext, int mode)
{
    int wave = threadIdx.x >> 6;
    int lane = threadIdx.x & 63;
    int node = blockIdx.x * 4 + wave;
    if (node >= N_NODES) return;
    int lb8  = lane * 4;                     // byte offset within fp8 row
    int lb16 = lane * 8;                     // byte offset within fp16 row
    const char* xlb = (const char*)xl8;

    uint2 xrr = *(const uint2*)((const char*)xrh + (size_t)node * (HCDIM * 2) + lb16);
    h2 xra = bch2(xrr.x), xrb = bch2(xrr.y);
    float4 at4 = *(const float4*)&att[lane * 4];
    // pre-scale attention by log2(e): scores come out ready for exp2
    h2 ata = {(_Float16)(at4.x * LOG2E), (_Float16)(at4.y * LOG2E)};
    h2 atb = {(_Float16)(at4.z * LOG2E), (_Float16)(at4.w * LOG2E)};

    int e0 = rowptr[node], e1 = rowptr[node + 1];
    float denom = 0.f;
    float4 acc = make_float4(0.f, 0.f, 0.f, 0.f);

    unsigned int d[4];
    #pragma unroll
    for (int k = 0; k < 4; ++k)
        d[k] = *(const unsigned int*)(xlb + (size_t)(unsigned)colx[e0 + k] + lb8);

    for (int e = e0; e < e1; e += 4) {
        unsigned int nd[4];
        #pragma unroll
        for (int k = 0; k < 4; ++k)
            nd[k] = *(const unsigned int*)(xlb + (size_t)(unsigned)colx[e + 4 + k] + lb8);

        f32x2 lo[4], hi[4];
        float p[4];
        #pragma unroll
        for (int k = 0; k < 4; ++k) {
            lo[k] = __builtin_amdgcn_cvt_pk_f32_fp8(d[k], false);
            hi[k] = __builtin_amdgcn_cvt_pk_f32_fp8(d[k], true);
            h2 a = pk16(lo[k].x, lo[k].y);
            h2 b = pk16(hi[k].x, hi[k].y);
            h2 la = lrelu2(a + xra);
            h2 lbv = lrelu2(b + xrb);
            float pp = __builtin_amdgcn_fdot2(la, ata, 0.f, false);
            p[k] = __builtin_amdgcn_fdot2(lbv, atb, pp, false);
        }
        #pragma unroll
        for (int off = 1; off <= 8; off <<= 1) {
            #pragma unroll
            for (int k = 0; k < 4; ++k) p[k] += __shfl_xor(p[k], off, 64);
        }
        float w[4];
        #pragma unroll
        for (int k = 0; k < 4; ++k)
            w[k] = (e + k < e1) ? exp2f(p[k]) : 0.f;

        denom += (w[0] + w[1]) + (w[2] + w[3]);
        acc.x += w[0] * lo[0].x + w[1] * lo[1].x + w[2] * lo[2].x + w[3] * lo[3].x;
        acc.y += w[0] * lo[0].y + w[1] * lo[1].y + w[2] * lo[2].y + w[3] * lo[3].y;
        acc.z += w[0] * hi[0].x + w[1] * hi[1].x + w[2] * hi[2].x + w[3] * hi[3].x;
        acc.w += w[0] * hi[0].y + w[1] * hi[1].y + w[2] * hi[2].y + w[3] * hi[3].y;
        d[0] = nd[0]; d[1] = nd[1]; d[2] = nd[2]; d[3] = nd[3];
    }

    float inv = 1.f / denom;
    float4 b4 = *(const float4*)&bias[lane * 4];
    float ox = acc.x * inv + b4.x;
    float oy = acc.y * inv + b4.y;
    float oz = acc.z * inv + b4.z;
    float ow = acc.w * inv + b4.w;
    if (mode == 0) {
        f16x4 h;
        h.x = (_Float16)ox; h.y = (_Float16)oy;
        h.z = (_Float16)oz; h.w = (_Float16)ow;
        *(f16x4*)((char*)outh + (size_t)node * (HCDIM * 2) + lb16) = h;
    } else {
        f16x4 h;
        h.x = (_Float16)fmaxf(ox, 0.f); h.y = (_Float16)fmaxf(oy, 0.f);
        h.z = (_Float16)fmaxf(oz, 0.f); h.w = (_Float16)fmaxf(ow, 0.f);
        *(f16x4*)((char*)onext + (size_t)node * (HCDIM * 2) + lb16) = h;
    }
}

// ============================ Two-stage pooling ============================
__global__ __launch_bounds__(256) void pool_partial(
    const _Float16* __restrict__ h, const int* __restrict__ startg,
    const int* __restrict__ endg, float* __restrict__ sumP, float* __restrict__ maxP)
{
    __shared__ float4 sS[4][64];
    __shared__ float4 sM[4][64];
    int g = blockIdx.x >> 5, part = blockIdx.x & (NPART - 1);
    int lane = threadIdx.x & 63;
    int sub = threadIdx.x >> 6;
    int c0 = lane * 4;
    int s = startg[g], e = endg[g];
    float4 sum = make_float4(0.f, 0.f, 0.f, 0.f);
    float4 mx = make_float4(-INFINITY, -INFINITY, -INFINITY, -INFINITY);
    for (int i = s + part * 4 + sub; i < e; i += NPART * 4) {
        uint2 u = *(const uint2*)&h[(size_t)i * HCDIM + c0];
        h2 a = bch2(u.x), b = bch2(u.y);
        float4 v = make_float4((float)a.x, (float)a.y, (float)b.x, (float)b.y);
        sum.x += v.x; sum.y += v.y; sum.z += v.z; sum.w += v.w;
        mx.x = fmaxf(mx.x, v.x); mx.y = fmaxf(mx.y, v.y);
        mx.z = fmaxf(mx.z, v.z); mx.w = fmaxf(mx.w, v.w);
    }
    sS[sub][lane] = sum; sM[sub][lane] = mx;
    __syncthreads();
    if (sub == 0) {
        #pragma unroll
        for (int j = 1; j < 4; ++j) {
            float4 a = sS[j][lane], b = sM[j][lane];
            sum.x += a.x; sum.y += a.y; sum.z += a.z; sum.w += a.w;
            mx.x = fmaxf(mx.x, b.x); mx.y = fmaxf(mx.y, b.y);
            mx.z = fmaxf(mx.z, b.z); mx.w = fmaxf(mx.w, b.w);
        }
        size_t o = (size_t)blockIdx.x * HCDIM + c0;
        *(float4*)&sumP[o] = sum;
        *(float4*)&maxP[o] = mx;
    }
}

__global__ __launch_bounds__(256) void pool_final(
    const float* __restrict__ sumP, const float* __restrict__ maxP,
    const int* __restrict__ startg, const int* __restrict__ endg,
    float* __restrict__ p)
{
    int g = blockIdx.x, c = threadIdx.x;
    float s = 0.f, m = -INFINITY;
    #pragma unroll 8
    for (int part = 0; part < NPART; ++part) {
        size_t o = (size_t)(g * NPART + part) * HCDIM + c;
        s += sumP[o];
        m = fmaxf(m, maxP[o]);
    }
    int cnt = endg[g] - startg[g];
    float inv = 1.f / fmaxf((float)cnt, 1.f);
    p[(size_t)g * HCDIM + c] = s * inv + m;
}

// ============================ Head: logits + softmax ============================
__global__ void logits_kernel(const float* __restrict__ p, const float* __restrict__ Wout,
                              const float* __restrict__ bout, float* __restrict__ out)
{
    __shared__ float red[256];
    __shared__ float lg[NCLS];
    int g = blockIdx.x, t = threadIdx.x;
    float pv = p[g * HCDIM + t];
    for (int j = 0; j < NCLS; ++j) {
        red[t] = pv * Wout[t * NCLS + j];
        __syncthreads();
        for (int off = 128; off > 0; off >>= 1) {
            if (t < off) red[t] += red[t + off];
            __syncthreads();
        }
        if (t == 0) lg[j] = red[0] + bout[j];
        __syncthreads();
    }
    if (t == 0) {
        float mx = fmaxf(lg[0], fmaxf(lg[1], lg[2]));
        float e0 = __expf(lg[0] - mx), e1 = __expf(lg[1] - mx), e2 = __expf(lg[2] - mx);
        float inv = 1.f / (e0 + e1 + e2);
        out[g * NCLS + 0] = e0 * inv;
        out[g * NCLS + 1] = e1 * inv;
        out[g * NCLS + 2] = e2 * inv;
    }
}

// ============================ Orchestration ============================
extern "C" void kernel_launch(void* const* d_in, const int* in_sizes, int n_in,
                              void* d_out, int out_size, void* d_ws, size_t ws_size,
                              hipStream_t stream) {
    const float* x     = (const float*)d_in[0];
    const int*   ei    = (const int*)d_in[1];
    const int*   batch = (const int*)d_in[2];
    const float *Wl[3], *bl[3], *Wr[3], *br[3], *att[3], *bias[3];
    for (int li = 0; li < 3; ++li) {
        int b = 3 + li * 6;
        Wl[li]   = (const float*)d_in[b + 0];
        bl[li]   = (const float*)d_in[b + 1];
        Wr[li]   = (const float*)d_in[b + 2];
        br[li]   = (const float*)d_in[b + 3];
        att[li]  = (const float*)d_in[b + 4];
        bias[li] = (const float*)d_in[b + 5];
    }
    const float* Wout = (const float*)d_in[21];
    const float* bout = (const float*)d_in[22];
    float* out = (float*)d_out;

    size_t off = 0;
    char* wsb = (char*)d_ws;
    auto alloc = [&](size_t bytes) -> char* {
        char* ptr = wsb + off;
        off += (bytes + 255) & ~(size_t)255;
        return ptr;
    };
    // deg + startg + endg in one zero-init block (single memset)
    int* zblk    = (int*)alloc((N_NODES + 2 * NGRAPH) * sizeof(int));
    int* deg     = zblk;
    int* startg  = zblk + N_NODES;
    int* endg    = zblk + N_NODES + NGRAPH;
    int* rowptr  = (int*)alloc((N_NODES + 1) * sizeof(int));
    int* cursor  = (int*)alloc(N_NODES * sizeof(int));
    int* bsums   = (int*)alloc(256 * sizeof(int));
    int* colx    = (int*)alloc((size_t)(N_EDGES + N_NODES + 8) * sizeof(int));
    _Float16* Abuf = (_Float16*)alloc((size_t)MPAD * HCDIM * sizeof(_Float16));
    _Float16* Bt[3];
    for (int li = 0; li < 3; ++li) {
        int K = (li == 0) ? F_INPUT : HCDIM;
        Bt[li] = (_Float16*)alloc((size_t)512 * K * sizeof(_Float16));
    }
    unsigned char* xl8 = (unsigned char*)alloc((size_t)N_NODES * HCDIM);
    _Float16* xrh  = (_Float16*)alloc((size_t)N_NODES * HCDIM * sizeof(_Float16));
    _Float16* hbuf = (_Float16*)alloc((size_t)N_NODES * HCDIM * sizeof(_Float16));
    float* sumP    = (float*)alloc((size_t)NGRAPH * NPART * HCDIM * sizeof(float));
    float* maxP    = (float*)alloc((size_t)NGRAPH * NPART * HCDIM * sizeof(float));
    float* pbuf    = (float*)alloc((size_t)NGRAPH * HCDIM * sizeof(float));

    hipMemsetAsync(zblk, 0, (N_NODES + 2 * NGRAPH) * sizeof(int), stream);

    hist_boundary_kernel<<<HIST_NB + BND_NB, 256, 0, stream>>>(ei, deg, batch, startg, endg);
    block_scan_kernel<<<SCAN_NB, 256, 0, stream>>>(deg, rowptr, bsums);
    scan_bsums_kernel<<<1, 256, 0, stream>>>(bsums);
    add_off_kernel<<<SCAN_NB, 256, 0, stream>>>(rowptr, cursor, bsums);
    fill_kernel<<<(N_EDGES + N_NODES + 8 + 255) / 256, 256, 0, stream>>>(ei, cursor, colx);

    prep_kernel<<<PREP_NB, 256, 0, stream>>>(x, Abuf, Bt[0], Bt[1], Bt[2],
                                             Wl[0], Wr[0], Wl[1], Wr[1], Wl[2], Wr[2]);

    for (int li = 0; li < 3; ++li) {
        int K = (li == 0) ? F_INPUT : HCDIM;
        gemm_mfma<<<(MPAD / 64) * 4, 256, 0, stream>>>(
            Abuf, Bt[li], K, bl[li], br[li], xl8, xrh);
        if (li < 2) {
            gat_edge<<<N_NODES / 4, 256, 0, stream>>>(
                xl8, xrh, att[li], bias[li], rowptr, colx, nullptr, Abuf, 1);
        } else {
            gat_edge<<<N_NODES / 4, 256, 0, stream>>>(
                xl8, xrh, att[li], bias[li], rowptr, colx, hbuf, nullptr, 0);
        }
    }

    pool_partial<<<NGRAPH * NPART, 256, 0, stream>>>(hbuf, startg, endg, sumP, maxP);
    pool_final<<<NGRAPH, 256, 0, stream>>>(sumP, maxP, startg, endg, pbuf);
    logits_kernel<<<NGRAPH, 256, 0, stream>>>(pbuf, Wout, bout, out);
}

// Round 14
// 467.455 us; speedup vs baseline: 1.3705x; 1.0057x over previous
//
#include <hip/hip_runtime.h>
#include <math.h>

#define N_NODES 50000
#define N_EDGES 600000
#define F_INPUT 128
#define HCDIM 256
#define NGRAPH 64
#define NCLS 3
#define MPAD 50048   // 782 * 64, GEMM M padded
#define SCAN_NB ((N_NODES + 255) / 256)   // 196
#define LOG2E 1.4426950408889634f
#define NPART 32     // pooling partitions per graph

// fused prep kernel block ranges
#define SPLITX_NB (MPAD * F_INPUT / 4 / 256)            // 6256
#define ZERO_NB   (((MPAD - N_NODES) * HCDIM / 4 + 255) / 256)  // 12
#define WPREP_NB  (512 * (F_INPUT + HCDIM + HCDIM) / 256)       // 1280
#define PREP_NB   (SPLITX_NB + ZERO_NB + WPREP_NB)
// fused hist+boundary ranges
#define HIST_NB   ((N_EDGES + N_NODES + 255) / 256)     // 2540
#define BND_NB    ((N_NODES + 255) / 256)               // 196

typedef float f32x4 __attribute__((ext_vector_type(4)));
typedef float f32x2 __attribute__((ext_vector_type(2)));
typedef _Float16 f16x8 __attribute__((ext_vector_type(8)));
typedef _Float16 f16x4 __attribute__((ext_vector_type(4)));
typedef _Float16 h2 __attribute__((ext_vector_type(2)));

__device__ __forceinline__ void gl_lds16(const void* g, void* l) {
    __builtin_amdgcn_global_load_lds(
        (const __attribute__((address_space(1))) unsigned int*)g,
        (__attribute__((address_space(3))) unsigned int*)l, 16, 0, 0);
}

__device__ __forceinline__ h2 bch2(unsigned int u) { return __builtin_bit_cast(h2, u); }
__device__ __forceinline__ h2 pk16(float a, float b) {
    return __builtin_bit_cast(h2, __builtin_amdgcn_cvt_pkrtz(a, b));
}

// fp8x4 dword -> two fp16x2 (channels 0,1 and 2,3). fp8 values are exact in fp16.
#if __has_builtin(__builtin_amdgcn_cvt_pk_f16_fp8)
__device__ __forceinline__ void decode8(unsigned int d, h2& a, h2& b) {
    a = __builtin_bit_cast(h2, __builtin_amdgcn_cvt_pk_f16_fp8((short)(d & 0xffffu)));
    b = __builtin_bit_cast(h2, __builtin_amdgcn_cvt_pk_f16_fp8((short)(d >> 16)));
}
#else
__device__ __forceinline__ void decode8(unsigned int d, h2& a, h2& b) {
    f32x2 lo = __builtin_amdgcn_cvt_pk_f32_fp8(d, false);
    f32x2 hi = __builtin_amdgcn_cvt_pk_f32_fp8(d, true);
    a = pk16(lo.x, lo.y);
    b = pk16(hi.x, hi.y);
}
#endif

// packed leaky_relu(0.2): max(v,0) + 0.2*min(v,0)
__device__ __forceinline__ h2 lrelu2(h2 v) {
    const h2 z = {(_Float16)0.f, (_Float16)0.f};
    const h2 c = {(_Float16)0.2f, (_Float16)0.2f};
    h2 mx = __builtin_elementwise_max(v, z);
    h2 mn = __builtin_elementwise_min(v, z);
    return mx + mn * c;
}

// ============================ hist + boundary (fused) ============================
__global__ void hist_boundary_kernel(const int* __restrict__ ei, int* __restrict__ deg,
                                     const int* __restrict__ batch,
                                     int* __restrict__ startg, int* __restrict__ endg) {
    int b = blockIdx.x;
    if (b < HIST_NB) {
        int i = b * 256 + threadIdx.x;
        int total = N_EDGES + N_NODES;
        if (i >= total) return;
        int d = (i < N_EDGES) ? ei[N_EDGES + i] : (i - N_EDGES);
        atomicAdd(&deg[d], 1);
    } else {
        int i = (b - HIST_NB) * 256 + threadIdx.x;
        if (i >= N_NODES) return;
        int g = batch[i];
        if (i == 0 || batch[i - 1] != g) startg[g] = i;
        if (i == N_NODES - 1 || batch[i + 1] != g) endg[g] = i + 1;
    }
}

// ============================ CSR scan ============================
__global__ void block_scan_kernel(const int* __restrict__ deg, int* __restrict__ rowptr,
                                  int* __restrict__ bsums) {
    __shared__ int wt[4];
    int b = blockIdx.x, t = threadIdx.x, lane = t & 63, wid = t >> 6;
    int i = b * 256 + t;
    int v = (i < N_NODES) ? deg[i] : 0;
    int x = v;
    #pragma unroll
    for (int off = 1; off < 64; off <<= 1) {
        int y = __shfl_up(x, off, 64);
        if (lane >= off) x += y;
    }
    if (lane == 63) wt[wid] = x;
    __syncthreads();
    if (t == 0) {
        int s = 0;
        #pragma unroll
        for (int j = 0; j < 4; ++j) { int tv = wt[j]; wt[j] = s; s += tv; }
        bsums[b] = s;
    }
    __syncthreads();
    if (i < N_NODES) rowptr[i] = wt[wid] + x - v;
}

// add_off with in-block bsums prefix (replaces the separate 1-block scan kernel):
// each block sums bsums[0..b-1] with a tree reduce, then offsets its 256 rowptr entries.
__global__ void add_off_kernel(int* __restrict__ rowptr, int* __restrict__ cursor,
                               const int* __restrict__ bsums) {
    __shared__ int red[256];
    int b = blockIdx.x, t = threadIdx.x;
    red[t] = (t < b) ? bsums[t] : 0;   // b <= SCAN_NB-1 < 256
    __syncthreads();
    for (int off = 128; off > 0; off >>= 1) {
        if (t < off) red[t] += red[t + off];
        __syncthreads();
    }
    int offv = red[0];
    int i = b * 256 + t;
    if (i < N_NODES) {
        int r = rowptr[i] + offv;
        rowptr[i] = r;
        cursor[i] = r;
    }
    if (i == 0) rowptr[N_NODES] = N_EDGES + N_NODES;
}

// colx stores BYTE offsets into the fp8 xl matrix: s * HCDIM (256 B rows).
// Entries [total, total+8) are zero padding so the edge loop needs no prefetch clamps.
__global__ void fill_kernel(const int* __restrict__ ei, int* __restrict__ cursor,
                            int* __restrict__ colx) {
    int i = blockIdx.x * 256 + threadIdx.x;
    int total = N_EDGES + N_NODES;
    if (i >= total + 8) return;
    if (i >= total) { colx[i] = 0; return; }
    int s, d;
    if (i < N_EDGES) { s = ei[i]; d = ei[N_EDGES + i]; }
    else             { s = i - N_EDGES; d = s; }
    int pos = atomicAdd(&cursor[d], 1);
    colx[pos] = s * HCDIM;
}

// ============================ Fused prep: x->fp16, pad zero, W->fp16 n-major ============================
__global__ void prep_kernel(const float* __restrict__ x, _Float16* __restrict__ A,
                            _Float16* __restrict__ Bt0, _Float16* __restrict__ Bt1,
                            _Float16* __restrict__ Bt2,
                            const float* __restrict__ Wl0, const float* __restrict__ Wr0,
                            const float* __restrict__ Wl1, const float* __restrict__ Wr1,
                            const float* __restrict__ Wl2, const float* __restrict__ Wr2) {
    int b = blockIdx.x;
    if (b < SPLITX_NB) {
        int base = (b * 256 + threadIdx.x) * 4;
        int row = base >> 7;
        float4 v = make_float4(0.f, 0.f, 0.f, 0.f);
        if (row < N_NODES) v = *(const float4*)&x[base];
        f16x4 o;
        o.x = (_Float16)v.x; o.y = (_Float16)v.y; o.z = (_Float16)v.z; o.w = (_Float16)v.w;
        *(f16x4*)&A[base] = o;
    } else if (b < SPLITX_NB + ZERO_NB) {
        int i = ((b - SPLITX_NB) * 256 + threadIdx.x) * 4;
        if (i < (MPAD - N_NODES) * HCDIM) {
            f16x4 z = {(_Float16)0.f, (_Float16)0.f, (_Float16)0.f, (_Float16)0.f};
            *(f16x4*)&A[(size_t)N_NODES * HCDIM + i] = z;
        }
    } else {
        int t = (b - SPLITX_NB - ZERO_NB) * 256 + threadIdx.x;
        const float* Wl; const float* Wr; _Float16* Bt; int K;
        if (t < 512 * F_INPUT)            { Wl = Wl0; Wr = Wr0; Bt = Bt0; K = F_INPUT; }
        else if (t < 512 * (F_INPUT + HCDIM)) { t -= 512 * F_INPUT; Wl = Wl1; Wr = Wr1; Bt = Bt1; K = HCDIM; }
        else                              { t -= 512 * (F_INPUT + HCDIM); Wl = Wl2; Wr = Wr2; Bt = Bt2; K = HCDIM; }
        int n = t & 511, k = t >> 9;
        float w = (n < 256) ? Wl[k * 256 + n] : Wr[k * 256 + (n - 256)];
        Bt[n * K + k] = (_Float16)w;
    }
}

// ============================ fp16 MFMA GEMM, 64x128 tile, BK=64 ============================
__global__ __launch_bounds__(256) void gemm_mfma(
    const _Float16* __restrict__ A, const _Float16* __restrict__ B,
    int K,
    const float* __restrict__ bl, const float* __restrict__ br,
    unsigned char* __restrict__ xl8, _Float16* __restrict__ xrh)
{
    __shared__ _Float16 sA[64 * 64], sB[128 * 64];
    int tid = threadIdx.x;
    int lane = tid & 63, wave = tid >> 6;
    int wm = wave >> 1, wn = wave & 1;
    int bx = blockIdx.x >> 2, by = blockIdx.x & 3;
    int row0 = bx * 64;
    int n0 = by * 128;
    int quad = lane >> 4, l16 = lane & 15;

    f32x4 acc[2][4];
    #pragma unroll
    for (int i = 0; i < 2; ++i)
        #pragma unroll
        for (int j = 0; j < 4; ++j)
            acc[i][j] = (f32x4){0.f, 0.f, 0.f, 0.f};

    for (int k0 = 0; k0 < K; k0 += 64) {
        __syncthreads();
        #pragma unroll
        for (int pass = 0; pass < 2; ++pass) {
            int c = tid + pass * 256;           // A chunk 0..511
            int r = c >> 3;
            int pl = c & 7;
            int pg = pl ^ (r & 7);
            size_t ga = (size_t)(row0 + r) * K + k0 + pg * 8;
            gl_lds16(A + ga, sA + c * 8);
        }
        #pragma unroll
        for (int pass = 0; pass < 4; ++pass) {
            int c = tid + pass * 256;           // B chunk 0..1023
            int r = c >> 3;
            int pl = c & 7;
            int pg = pl ^ (r & 7);
            size_t gb = (size_t)(n0 + r) * K + k0 + pg * 8;
            gl_lds16(B + gb, sB + c * 8);
        }
        __syncthreads();

        #pragma unroll
        for (int kk = 0; kk < 2; ++kk) {
            f16x8 fa[2], fb[4];
            #pragma unroll
            for (int i = 0; i < 2; ++i) {
                int rr = wm * 32 + i * 16 + l16;
                int ca = (kk * 4 + quad) ^ (rr & 7);
                fa[i] = *(const f16x8*)&sA[rr * 64 + ca * 8];
            }
            #pragma unroll
            for (int j = 0; j < 4; ++j) {
                int nn = wn * 64 + j * 16 + l16;
                int cb = (kk * 4 + quad) ^ (nn & 7);
                fb[j] = *(const f16x8*)&sB[nn * 64 + cb * 8];
            }
            #pragma unroll
            for (int i = 0; i < 2; ++i)
                #pragma unroll
                for (int j = 0; j < 4; ++j)
                    acc[i][j] = __builtin_amdgcn_mfma_f32_16x16x32_f16(fa[i], fb[j], acc[i][j], 0, 0, 0);
        }
    }

    if (by < 2) {
        int cb0 = by * 128;
        #pragma unroll
        for (int j = 0; j < 4; ++j) {
            int col = cb0 + wn * 64 + j * 16 + l16;
            float bj = bl[col];
            #pragma unroll
            for (int i = 0; i < 2; ++i) {
                int rbase = row0 + wm * 32 + i * 16 + quad * 4;
                #pragma unroll
                for (int r = 0; r < 4; ++r) {
                    int row = rbase + r;
                    if (row < N_NODES) {
                        float v = acc[i][j][r] + bj;
                        int pk = __builtin_amdgcn_cvt_pk_fp8_f32(v, v, 0, false);
                        xl8[(size_t)row * HCDIM + col] = (unsigned char)pk;
                    }
                }
            }
        }
    } else {
        int cb0 = (by - 2) * 128;
        #pragma unroll
        for (int j = 0; j < 4; ++j) {
            int col = cb0 + wn * 64 + j * 16 + l16;
            float bj = br[col];
            #pragma unroll
            for (int i = 0; i < 2; ++i) {
                int rbase = row0 + wm * 32 + i * 16 + quad * 4;
                #pragma unroll
                for (int r = 0; r < 4; ++r) {
                    int row = rbase + r;
                    if (row < N_NODES)
                        xrh[(size_t)row * HCDIM + col] = (_Float16)(acc[i][j][r] + bj);
                }
            }
        }
    }
}

// ============================ Edge phase: fp8 gather, lean 4-edge unroll ============================
// Tail masking hoisted to a wave-uniform branch; gather offsets are 32-bit (saddr form);
// fp8->fp16 direct decode; acc stays fp32 (no-max softmax weights can reach e^30).
__global__ __launch_bounds__(256) void gat_edge(
    const unsigned char* __restrict__ xl8, const _Float16* __restrict__ xrh,
    const float* __restrict__ att, const float* __restrict__ bias,
    const int* __restrict__ rowptr, const int* __restrict__ colx,
    _Float16* __restrict__ outh, _Float16* __restrict__ onext, int mode)
{
    int wave = threadIdx.x >> 6;
    int lane = threadIdx.x & 63;
    int node = blockIdx.x * 4 + wave;
    if (node >= N_NODES) return;
    int lb8  = lane * 4;                     // byte offset within fp8 row
    int lb16 = lane * 8;                     // byte offset within fp16 row

    uint2 xrr = *(const uint2*)((const char*)xrh + (size_t)node * (HCDIM * 2) + lb16);
    h2 xra = bch2(xrr.x), xrb = bch2(xrr.y);
    float4 at4 = *(const float4*)&att[lane * 4];
    h2 ata = {(_Float16)(at4.x * LOG2E), (_Float16)(at4.y * LOG2E)};
    h2 atb = {(_Float16)(at4.z * LOG2E), (_Float16)(at4.w * LOG2E)};

    int e0 = rowptr[node], e1 = rowptr[node + 1];
    float denom = 0.f;
    float4 acc = make_float4(0.f, 0.f, 0.f, 0.f);

    unsigned int d[4];
    #pragma unroll
    for (int k = 0; k < 4; ++k)
        d[k] = *(const unsigned int*)(xl8 + (unsigned)(colx[e0 + k] + lb8));

    for (int e = e0; e < e1; e += 4) {
        unsigned int nd[4];
        #pragma unroll
        for (int k = 0; k < 4; ++k)
            nd[k] = *(const unsigned int*)(xl8 + (unsigned)(colx[e + 4 + k] + lb8));

        h2 a[4], b[4];
        float p[4];
        #pragma unroll
        for (int k = 0; k < 4; ++k) {
            decode8(d[k], a[k], b[k]);
            h2 la = lrelu2(a[k] + xra);
            h2 lbv = lrelu2(b[k] + xrb);
            float pp = __builtin_amdgcn_fdot2(la, ata, 0.f, false);
            p[k] = __builtin_amdgcn_fdot2(lbv, atb, pp, false);
        }
        #pragma unroll
        for (int off = 1; off <= 8; off <<= 1) {
            #pragma unroll
            for (int k = 0; k < 4; ++k) p[k] += __shfl_xor(p[k], off, 64);
        }
        float w[4];
        if (e + 4 <= e1) {                 // wave-uniform: full group, no masking
            #pragma unroll
            for (int k = 0; k < 4; ++k) w[k] = exp2f(p[k]);
        } else {                           // tail group only
            #pragma unroll
            for (int k = 0; k < 4; ++k) w[k] = (e + k < e1) ? exp2f(p[k]) : 0.f;
        }

        denom += (w[0] + w[1]) + (w[2] + w[3]);
        acc.x += w[0] * (float)a[0].x + w[1] * (float)a[1].x + w[2] * (float)a[2].x + w[3] * (float)a[3].x;
        acc.y += w[0] * (float)a[0].y + w[1] * (float)a[1].y + w[2] * (float)a[2].y + w[3] * (float)a[3].y;
        acc.z += w[0] * (float)b[0].x + w[1] * (float)b[1].x + w[2] * (float)b[2].x + w[3] * (float)b[3].x;
        acc.w += w[0] * (float)b[0].y + w[1] * (float)b[1].y + w[2] * (float)b[2].y + w[3] * (float)b[3].y;
        d[0] = nd[0]; d[1] = nd[1]; d[2] = nd[2]; d[3] = nd[3];
    }

    float inv = 1.f / denom;
    float4 b4 = *(const float4*)&bias[lane * 4];
    float ox = acc.x * inv + b4.x;
    float oy = acc.y * inv + b4.y;
    float oz = acc.z * inv + b4.z;
    float ow = acc.w * inv + b4.w;
    if (mode == 0) {
        f16x4 h;
        h.x = (_Float16)ox; h.y = (_Float16)oy;
        h.z = (_Float16)oz; h.w = (_Float16)ow;
        *(f16x4*)((char*)outh + (size_t)node * (HCDIM * 2) + lb16) = h;
    } else {
        f16x4 h;
        h.x = (_Float16)fmaxf(ox, 0.f); h.y = (_Float16)fmaxf(oy, 0.f);
        h.z = (_Float16)fmaxf(oz, 0.f); h.w = (_Float16)fmaxf(ow, 0.f);
        *(f16x4*)((char*)onext + (size_t)node * (HCDIM * 2) + lb16) = h;
    }
}

// ============================ Two-stage pooling ============================
__global__ __launch_bounds__(256) void pool_partial(
    const _Float16* __restrict__ h, const int* __restrict__ startg,
    const int* __restrict__ endg, float* __restrict__ sumP, float* __restrict__ maxP)
{
    __shared__ float4 sS[4][64];
    __shared__ float4 sM[4][64];
    int g = blockIdx.x >> 5, part = blockIdx.x & (NPART - 1);
    int lane = threadIdx.x & 63;
    int sub = threadIdx.x >> 6;
    int c0 = lane * 4;
    int s = startg[g], e = endg[g];
    float4 sum = make_float4(0.f, 0.f, 0.f, 0.f);
    float4 mx = make_float4(-INFINITY, -INFINITY, -INFINITY, -INFINITY);
    for (int i = s + part * 4 + sub; i < e; i += NPART * 4) {
        uint2 u = *(const uint2*)&h[(size_t)i * HCDIM + c0];
        h2 a = bch2(u.x), b = bch2(u.y);
        float4 v = make_float4((float)a.x, (float)a.y, (float)b.x, (float)b.y);
        sum.x += v.x; sum.y += v.y; sum.z += v.z; sum.w += v.w;
        mx.x = fmaxf(mx.x, v.x); mx.y = fmaxf(mx.y, v.y);
        mx.z = fmaxf(mx.z, v.z); mx.w = fmaxf(mx.w, v.w);
    }
    sS[sub][lane] = sum; sM[sub][lane] = mx;
    __syncthreads();
    if (sub == 0) {
        #pragma unroll
        for (int j = 1; j < 4; ++j) {
            float4 a = sS[j][lane], b = sM[j][lane];
            sum.x += a.x; sum.y += a.y; sum.z += a.z; sum.w += a.w;
            mx.x = fmaxf(mx.x, b.x); mx.y = fmaxf(mx.y, b.y);
            mx.z = fmaxf(mx.z, b.z); mx.w = fmaxf(mx.w, b.w);
        }
        size_t o = (size_t)blockIdx.x * HCDIM + c0;
        *(float4*)&sumP[o] = sum;
        *(float4*)&maxP[o] = mx;
    }
}

// Stage 2 + logits + softmax fused: thread c combines NPART partials for channel c,
// then the block reduces p·Wout and writes softmax'd class probs.
__global__ __launch_bounds__(256) void pool_final_logits(
    const float* __restrict__ sumP, const float* __restrict__ maxP,
    const int* __restrict__ startg, const int* __restrict__ endg,
    const float* __restrict__ Wout, const float* __restrict__ bout,
    float* __restrict__ out)
{
    __shared__ float red[256];
    __shared__ float lg[NCLS];
    int g = blockIdx.x, c = threadIdx.x;
    float s = 0.f, m = -INFINITY;
    #pragma unroll 8
    for (int part = 0; part < NPART; ++part) {
        size_t o = (size_t)(g * NPART + part) * HCDIM + c;
        s += sumP[o];
        m = fmaxf(m, maxP[o]);
    }
    int cnt = endg[g] - startg[g];
    float inv = 1.f / fmaxf((float)cnt, 1.f);
    float pv = s * inv + m;

    for (int j = 0; j < NCLS; ++j) {
        red[c] = pv * Wout[c * NCLS + j];
        __syncthreads();
        for (int off = 128; off > 0; off >>= 1) {
            if (c < off) red[c] += red[c + off];
            __syncthreads();
        }
        if (c == 0) lg[j] = red[0] + bout[j];
        __syncthreads();
    }
    if (c == 0) {
        float mx = fmaxf(lg[0], fmaxf(lg[1], lg[2]));
        float e0 = __expf(lg[0] - mx), e1 = __expf(lg[1] - mx), e2 = __expf(lg[2] - mx);
        float invs = 1.f / (e0 + e1 + e2);
        out[g * NCLS + 0] = e0 * invs;
        out[g * NCLS + 1] = e1 * invs;
        out[g * NCLS + 2] = e2 * invs;
    }
}

// ============================ Orchestration ============================
extern "C" void kernel_launch(void* const* d_in, const int* in_sizes, int n_in,
                              void* d_out, int out_size, void* d_ws, size_t ws_size,
                              hipStream_t stream) {
    const float* x     = (const float*)d_in[0];
    const int*   ei    = (const int*)d_in[1];
    const int*   batch = (const int*)d_in[2];
    const float *Wl[3], *bl[3], *Wr[3], *br[3], *att[3], *bias[3];
    for (int li = 0; li < 3; ++li) {
        int b = 3 + li * 6;
        Wl[li]   = (const float*)d_in[b + 0];
        bl[li]   = (const float*)d_in[b + 1];
        Wr[li]   = (const float*)d_in[b + 2];
        br[li]   = (const float*)d_in[b + 3];
        att[li]  = (const float*)d_in[b + 4];
        bias[li] = (const float*)d_in[b + 5];
    }
    const float* Wout = (const float*)d_in[21];
    const float* bout = (const float*)d_in[22];
    float* out = (float*)d_out;

    size_t off = 0;
    char* wsb = (char*)d_ws;
    auto alloc = [&](size_t bytes) -> char* {
        char* ptr = wsb + off;
        off += (bytes + 255) & ~(size_t)255;
        return ptr;
    };
    // deg + startg + endg in one zero-init block (single memset)
    int* zblk    = (int*)alloc((N_NODES + 2 * NGRAPH) * sizeof(int));
    int* deg     = zblk;
    int* startg  = zblk + N_NODES;
    int* endg    = zblk + N_NODES + NGRAPH;
    int* rowptr  = (int*)alloc((N_NODES + 1) * sizeof(int));
    int* cursor  = (int*)alloc(N_NODES * sizeof(int));
    int* bsums   = (int*)alloc(256 * sizeof(int));
    int* colx    = (int*)alloc((size_t)(N_EDGES + N_NODES + 8) * sizeof(int));
    _Float16* Abuf = (_Float16*)alloc((size_t)MPAD * HCDIM * sizeof(_Float16));
    _Float16* Bt[3];
    for (int li = 0; li < 3; ++li) {
        int K = (li == 0) ? F_INPUT : HCDIM;
        Bt[li] = (_Float16*)alloc((size_t)512 * K * sizeof(_Float16));
    }
    unsigned char* xl8 = (unsigned char*)alloc((size_t)N_NODES * HCDIM);
    _Float16* xrh  = (_Float16*)alloc((size_t)N_NODES * HCDIM * sizeof(_Float16));
    _Float16* hbuf = (_Float16*)alloc((size_t)N_NODES * HCDIM * sizeof(_Float16));
    float* sumP    = (float*)alloc((size_t)NGRAPH * NPART * HCDIM * sizeof(float));
    float* maxP    = (float*)alloc((size_t)NGRAPH * NPART * HCDIM * sizeof(float));

    hipMemsetAsync(zblk, 0, (N_NODES + 2 * NGRAPH) * sizeof(int), stream);

    hist_boundary_kernel<<<HIST_NB + BND_NB, 256, 0, stream>>>(ei, deg, batch, startg, endg);
    block_scan_kernel<<<SCAN_NB, 256, 0, stream>>>(deg, rowptr, bsums);
    add_off_kernel<<<SCAN_NB, 256, 0, stream>>>(rowptr, cursor, bsums);
    fill_kernel<<<(N_EDGES + N_NODES + 8 + 255) / 256, 256, 0, stream>>>(ei, cursor, colx);

    prep_kernel<<<PREP_NB, 256, 0, stream>>>(x, Abuf, Bt[0], Bt[1], Bt[2],
                                             Wl[0], Wr[0], Wl[1], Wr[1], Wl[2], Wr[2]);

    for (int li = 0; li < 3; ++li) {
        int K = (li == 0) ? F_INPUT : HCDIM;
        gemm_mfma<<<(MPAD / 64) * 4, 256, 0, stream>>>(
            Abuf, Bt[li], K, bl[li], br[li], xl8, xrh);
        if (li < 2) {
            gat_edge<<<N_NODES / 4, 256, 0, stream>>>(
                xl8, xrh, att[li], bias[li], rowptr, colx, nullptr, Abuf, 1);
        } else {
            gat_edge<<<N_NODES / 4, 256, 0, stream>>>(
                xl8, xrh, att[li], bias[li], rowptr, colx, hbuf, nullptr, 0);
        }
    }

    pool_partial<<<NGRAPH * NPART, 256, 0, stream>>>(hbuf, startg, endg, sumP, maxP);
    pool_final_logits<<<NGRAPH, 256, 0, stream>>>(sumP, maxP, startg, endg, Wout, bout, out);
}

// Round 15
// 451.097 us; speedup vs baseline: 1.4202x; 1.0363x over previous
//
#include <hip/hip_runtime.h>
#include <math.h>

#define N_NODES 50000
#define N_EDGES 600000
#define F_INPUT 128
#define HCDIM 256
#define NGRAPH 64
#define NCLS 3
#define MPAD 50048   // 782 * 64, GEMM M padded
#define SCAN_NB ((N_NODES + 255) / 256)   // 196
#define LOG2E 1.4426950408889634f
#define NPART 32     // pooling partitions per graph

// fused prep kernel block ranges
#define SPLITX_NB (MPAD * F_INPUT / 4 / 256)            // 6256
#define ZERO_NB   (((MPAD - N_NODES) * HCDIM / 4 + 255) / 256)  // 12
#define WPREP_NB  (512 * (F_INPUT + HCDIM + HCDIM) / 256)       // 1280
#define PREP_NB   (SPLITX_NB + ZERO_NB + WPREP_NB)
// fused hist+boundary ranges
#define HIST_NB   ((N_EDGES + N_NODES + 255) / 256)     // 2540
#define BND_NB    ((N_NODES + 255) / 256)               // 196

typedef float f32x4 __attribute__((ext_vector_type(4)));
typedef float f32x2 __attribute__((ext_vector_type(2)));
typedef _Float16 f16x8 __attribute__((ext_vector_type(8)));
typedef _Float16 f16x4 __attribute__((ext_vector_type(4)));
typedef _Float16 h2 __attribute__((ext_vector_type(2)));

__device__ __forceinline__ void gl_lds16(const void* g, void* l) {
    __builtin_amdgcn_global_load_lds(
        (const __attribute__((address_space(1))) unsigned int*)g,
        (__attribute__((address_space(3))) unsigned int*)l, 16, 0, 0);
}

__device__ __forceinline__ h2 bch2(unsigned int u) { return __builtin_bit_cast(h2, u); }
__device__ __forceinline__ h2 pk16(float a, float b) {
    return __builtin_bit_cast(h2, __builtin_amdgcn_cvt_pkrtz(a, b));
}

// packed leaky_relu(0.2): max(v,0) + 0.2*min(v,0)
__device__ __forceinline__ h2 lrelu2(h2 v) {
    const h2 z = {(_Float16)0.f, (_Float16)0.f};
    const h2 c = {(_Float16)0.2f, (_Float16)0.2f};
    h2 mx = __builtin_elementwise_max(v, z);
    h2 mn = __builtin_elementwise_min(v, z);
    return mx + mn * c;
}

// ============================ hist + boundary (fused) ============================
__global__ void hist_boundary_kernel(const int* __restrict__ ei, int* __restrict__ deg,
                                     const int* __restrict__ batch,
                                     int* __restrict__ startg, int* __restrict__ endg) {
    int b = blockIdx.x;
    if (b < HIST_NB) {
        int i = b * 256 + threadIdx.x;
        int total = N_EDGES + N_NODES;
        if (i >= total) return;
        int d = (i < N_EDGES) ? ei[N_EDGES + i] : (i - N_EDGES);
        atomicAdd(&deg[d], 1);
    } else {
        int i = (b - HIST_NB) * 256 + threadIdx.x;
        if (i >= N_NODES) return;
        int g = batch[i];
        if (i == 0 || batch[i - 1] != g) startg[g] = i;
        if (i == N_NODES - 1 || batch[i + 1] != g) endg[g] = i + 1;
    }
}

// ============================ CSR scan ============================
__global__ void block_scan_kernel(const int* __restrict__ deg, int* __restrict__ rowptr,
                                  int* __restrict__ bsums) {
    __shared__ int wt[4];
    int b = blockIdx.x, t = threadIdx.x, lane = t & 63, wid = t >> 6;
    int i = b * 256 + t;
    int v = (i < N_NODES) ? deg[i] : 0;
    int x = v;
    #pragma unroll
    for (int off = 1; off < 64; off <<= 1) {
        int y = __shfl_up(x, off, 64);
        if (lane >= off) x += y;
    }
    if (lane == 63) wt[wid] = x;
    __syncthreads();
    if (t == 0) {
        int s = 0;
        #pragma unroll
        for (int j = 0; j < 4; ++j) { int tv = wt[j]; wt[j] = s; s += tv; }
        bsums[b] = s;
    }
    __syncthreads();
    if (i < N_NODES) rowptr[i] = wt[wid] + x - v;
}

// add_off with in-block bsums prefix (replaces the separate 1-block scan kernel)
__global__ void add_off_kernel(int* __restrict__ rowptr, int* __restrict__ cursor,
                               const int* __restrict__ bsums) {
    __shared__ int red[256];
    int b = blockIdx.x, t = threadIdx.x;
    red[t] = (t < b) ? bsums[t] : 0;   // b <= SCAN_NB-1 < 256
    __syncthreads();
    for (int off = 128; off > 0; off >>= 1) {
        if (t < off) red[t] += red[t + off];
        __syncthreads();
    }
    int offv = red[0];
    int i = b * 256 + t;
    if (i < N_NODES) {
        int r = rowptr[i] + offv;
        rowptr[i] = r;
        cursor[i] = r;
    }
    if (i == 0) rowptr[N_NODES] = N_EDGES + N_NODES;
}

// colx stores BYTE offsets into the fp8 xl matrix: s * HCDIM (256 B rows).
// Entries [total, total+8) are zero padding so the edge loop needs no prefetch clamps.
__global__ void fill_kernel(const int* __restrict__ ei, int* __restrict__ cursor,
                            int* __restrict__ colx) {
    int i = blockIdx.x * 256 + threadIdx.x;
    int total = N_EDGES + N_NODES;
    if (i >= total + 8) return;
    if (i >= total) { colx[i] = 0; return; }
    int s, d;
    if (i < N_EDGES) { s = ei[i]; d = ei[N_EDGES + i]; }
    else             { s = i - N_EDGES; d = s; }
    int pos = atomicAdd(&cursor[d], 1);
    colx[pos] = s * HCDIM;
}

// ============================ Fused prep: x->fp16, pad zero, W->fp16 n-major ============================
__global__ void prep_kernel(const float* __restrict__ x, _Float16* __restrict__ A,
                            _Float16* __restrict__ Bt0, _Float16* __restrict__ Bt1,
                            _Float16* __restrict__ Bt2,
                            const float* __restrict__ Wl0, const float* __restrict__ Wr0,
                            const float* __restrict__ Wl1, const float* __restrict__ Wr1,
                            const float* __restrict__ Wl2, const float* __restrict__ Wr2) {
    int b = blockIdx.x;
    if (b < SPLITX_NB) {
        int base = (b * 256 + threadIdx.x) * 4;
        int row = base >> 7;
        float4 v = make_float4(0.f, 0.f, 0.f, 0.f);
        if (row < N_NODES) v = *(const float4*)&x[base];
        f16x4 o;
        o.x = (_Float16)v.x; o.y = (_Float16)v.y; o.z = (_Float16)v.z; o.w = (_Float16)v.w;
        *(f16x4*)&A[base] = o;
    } else if (b < SPLITX_NB + ZERO_NB) {
        int i = ((b - SPLITX_NB) * 256 + threadIdx.x) * 4;
        if (i < (MPAD - N_NODES) * HCDIM) {
            f16x4 z = {(_Float16)0.f, (_Float16)0.f, (_Float16)0.f, (_Float16)0.f};
            *(f16x4*)&A[(size_t)N_NODES * HCDIM + i] = z;
        }
    } else {
        int t = (b - SPLITX_NB - ZERO_NB) * 256 + threadIdx.x;
        const float* Wl; const float* Wr; _Float16* Bt; int K;
        if (t < 512 * F_INPUT)            { Wl = Wl0; Wr = Wr0; Bt = Bt0; K = F_INPUT; }
        else if (t < 512 * (F_INPUT + HCDIM)) { t -= 512 * F_INPUT; Wl = Wl1; Wr = Wr1; Bt = Bt1; K = HCDIM; }
        else                              { t -= 512 * (F_INPUT + HCDIM); Wl = Wl2; Wr = Wr2; Bt = Bt2; K = HCDIM; }
        int n = t & 511, k = t >> 9;
        float w = (n < 256) ? Wl[k * 256 + n] : Wr[k * 256 + (n - 256)];
        Bt[n * K + k] = (_Float16)w;
    }
}

// ============================ fp16 MFMA GEMM, 64x128 tile, BK=64 ============================
__global__ __launch_bounds__(256) void gemm_mfma(
    const _Float16* __restrict__ A, const _Float16* __restrict__ B,
    int K,
    const float* __restrict__ bl, const float* __restrict__ br,
    unsigned char* __restrict__ xl8, _Float16* __restrict__ xrh)
{
    __shared__ _Float16 sA[64 * 64], sB[128 * 64];
    int tid = threadIdx.x;
    int lane = tid & 63, wave = tid >> 6;
    int wm = wave >> 1, wn = wave & 1;
    int bx = blockIdx.x >> 2, by = blockIdx.x & 3;
    int row0 = bx * 64;
    int n0 = by * 128;
    int quad = lane >> 4, l16 = lane & 15;

    f32x4 acc[2][4];
    #pragma unroll
    for (int i = 0; i < 2; ++i)
        #pragma unroll
        for (int j = 0; j < 4; ++j)
            acc[i][j] = (f32x4){0.f, 0.f, 0.f, 0.f};

    for (int k0 = 0; k0 < K; k0 += 64) {
        __syncthreads();
        #pragma unroll
        for (int pass = 0; pass < 2; ++pass) {
            int c = tid + pass * 256;           // A chunk 0..511
            int r = c >> 3;
            int pl = c & 7;
            int pg = pl ^ (r & 7);
            size_t ga = (size_t)(row0 + r) * K + k0 + pg * 8;
            gl_lds16(A + ga, sA + c * 8);
        }
        #pragma unroll
        for (int pass = 0; pass < 4; ++pass) {
            int c = tid + pass * 256;           // B chunk 0..1023
            int r = c >> 3;
            int pl = c & 7;
            int pg = pl ^ (r & 7);
            size_t gb = (size_t)(n0 + r) * K + k0 + pg * 8;
            gl_lds16(B + gb, sB + c * 8);
        }
        __syncthreads();

        #pragma unroll
        for (int kk = 0; kk < 2; ++kk) {
            f16x8 fa[2], fb[4];
            #pragma unroll
            for (int i = 0; i < 2; ++i) {
                int rr = wm * 32 + i * 16 + l16;
                int ca = (kk * 4 + quad) ^ (rr & 7);
                fa[i] = *(const f16x8*)&sA[rr * 64 + ca * 8];
            }
            #pragma unroll
            for (int j = 0; j < 4; ++j) {
                int nn = wn * 64 + j * 16 + l16;
                int cb = (kk * 4 + quad) ^ (nn & 7);
                fb[j] = *(const f16x8*)&sB[nn * 64 + cb * 8];
            }
            #pragma unroll
            for (int i = 0; i < 2; ++i)
                #pragma unroll
                for (int j = 0; j < 4; ++j)
                    acc[i][j] = __builtin_amdgcn_mfma_f32_16x16x32_f16(fa[i], fb[j], acc[i][j], 0, 0, 0);
        }
    }

    if (by < 2) {
        int cb0 = by * 128;
        #pragma unroll
        for (int j = 0; j < 4; ++j) {
            int col = cb0 + wn * 64 + j * 16 + l16;
            float bj = bl[col];
            #pragma unroll
            for (int i = 0; i < 2; ++i) {
                int rbase = row0 + wm * 32 + i * 16 + quad * 4;
                #pragma unroll
                for (int r = 0; r < 4; ++r) {
                    int row = rbase + r;
                    if (row < N_NODES) {
                        float v = acc[i][j][r] + bj;
                        int pk = __builtin_amdgcn_cvt_pk_fp8_f32(v, v, 0, false);
                        xl8[(size_t)row * HCDIM + col] = (unsigned char)pk;
                    }
                }
            }
        }
    } else {
        int cb0 = (by - 2) * 128;
        #pragma unroll
        for (int j = 0; j < 4; ++j) {
            int col = cb0 + wn * 64 + j * 16 + l16;
            float bj = br[col];
            #pragma unroll
            for (int i = 0; i < 2; ++i) {
                int rbase = row0 + wm * 32 + i * 16 + quad * 4;
                #pragma unroll
                for (int r = 0; r < 4; ++r) {
                    int row = rbase + r;
                    if (row < N_NODES)
                        xrh[(size_t)row * HCDIM + col] = (_Float16)(acc[i][j][r] + bj);
                }
            }
        }
    }
}

// ============================ Edge phase: quarter-wave per edge ============================
// 16 lanes per edge, 16 channels/lane (16 B fp8 = one dwordx4 gather per edge group of 4).
// Lane (q=lane>>4, ql=lane&15): edge slot q, channels [ql*16, ql*16+16) — one head per lane
// (head = ql>>2). Score reduce = 2 ds_swizzle stages within 4 lanes; exp2 once per lane;
// cross-quarter acc/denom reduce (xor 16/32) once per NODE. colx padded +8 → no clamps.
__global__ __launch_bounds__(256) void gat_edge(
    const unsigned char* __restrict__ xl8, const _Float16* __restrict__ xrh,
    const float* __restrict__ att, const float* __restrict__ bias,
    const int* __restrict__ rowptr, const int* __restrict__ colx,
    _Float16* __restrict__ outh, _Float16* __restrict__ onext, int mode)
{
    int wave = threadIdx.x >> 6;
    int lane = threadIdx.x & 63;
    int q  = lane >> 4;          // edge slot in group
    int ql = lane & 15;          // channel group: ch [ql*16, ql*16+16)
    int node = blockIdx.x * 4 + wave;
    if (node >= N_NODES) return;
    int cb = ql * 16;            // first channel / fp8 byte offset in row

    // xr channels cb..cb+15 (fp16, 32 B)
    const char* xrrow = (const char*)xrh + (size_t)node * (HCDIM * 2) + cb * 2;
    uint4 xu0 = *(const uint4*)xrrow;
    uint4 xu1 = *(const uint4*)(xrrow + 16);
    h2 xr[8] = { bch2(xu0.x), bch2(xu0.y), bch2(xu0.z), bch2(xu0.w),
                 bch2(xu1.x), bch2(xu1.y), bch2(xu1.z), bch2(xu1.w) };
    h2 at[8];
    #pragma unroll
    for (int i = 0; i < 8; ++i) {
        float2 av = *(const float2*)&att[cb + i * 2];
        at[i] = (h2){(_Float16)(av.x * LOG2E), (_Float16)(av.y * LOG2E)};
    }

    int e0 = rowptr[node], e1 = rowptr[node + 1];
    float denom = 0.f;
    float acc[16];
    #pragma unroll
    for (int i = 0; i < 16; ++i) acc[i] = 0.f;

    uint4 d = *(const uint4*)(xl8 + (unsigned)(colx[e0 + q] + cb));

    for (int e = e0; e < e1; e += 4) {
        uint4 nd = *(const uint4*)(xl8 + (unsigned)(colx[e + 4 + q] + cb));

        // decode 16 fp8 -> f32 pairs (for acc) + h2 (for score)
        unsigned int dw[4] = {d.x, d.y, d.z, d.w};
        f32x2 flo[4], fhi[4];
        h2 hx[8];
        #pragma unroll
        for (int j = 0; j < 4; ++j) {
            flo[j] = __builtin_amdgcn_cvt_pk_f32_fp8(dw[j], false);
            fhi[j] = __builtin_amdgcn_cvt_pk_f32_fp8(dw[j], true);
            hx[2 * j]     = pk16(flo[j].x, flo[j].y);
            hx[2 * j + 1] = pk16(fhi[j].x, fhi[j].y);
        }
        // score over own 16 channels (two 4-deep fdot2 chains)
        float pa = 0.f, pb = 0.f;
        #pragma unroll
        for (int i = 0; i < 4; ++i) {
            pa = __builtin_amdgcn_fdot2(lrelu2(hx[i] + xr[i]), at[i], pa, false);
            pb = __builtin_amdgcn_fdot2(lrelu2(hx[i + 4] + xr[i + 4]), at[i + 4], pb, false);
        }
        float p = pa + pb;
        // head reduce: 4 lanes (ql within head group) — xor1, xor2 via imm ds_swizzle
        p += __builtin_bit_cast(float, __builtin_amdgcn_ds_swizzle(__builtin_bit_cast(int, p), 0x041F));
        p += __builtin_bit_cast(float, __builtin_amdgcn_ds_swizzle(__builtin_bit_cast(int, p), 0x081F));

        float w;
        if (e + 4 <= e1) {
            w = exp2f(p);
        } else {
            w = (e + q < e1) ? exp2f(p) : 0.f;
        }
        denom += w;
        #pragma unroll
        for (int j = 0; j < 4; ++j) {
            acc[4 * j]     += w * flo[j].x;
            acc[4 * j + 1] += w * flo[j].y;
            acc[4 * j + 2] += w * fhi[j].x;
            acc[4 * j + 3] += w * fhi[j].y;
        }
        d = nd;
    }

    // cross-quarter reduce (edges were split over the 4 quarters; ql/head invariant)
    denom += __shfl_xor(denom, 16, 64);
    denom += __shfl_xor(denom, 32, 64);
    #pragma unroll
    for (int i = 0; i < 16; ++i) {
        acc[i] += __shfl_xor(acc[i], 16, 64);
        acc[i] += __shfl_xor(acc[i], 32, 64);
    }

    if (q == 0) {
        float inv = 1.f / denom;
        char* orow = (char*)(mode == 0 ? outh : onext) + (size_t)node * (HCDIM * 2) + cb * 2;
        h2 o[8];
        #pragma unroll
        for (int i = 0; i < 8; ++i) {
            float2 bv = *(const float2*)&bias[cb + i * 2];
            float v0 = acc[2 * i] * inv + bv.x;
            float v1 = acc[2 * i + 1] * inv + bv.y;
            if (mode != 0) { v0 = fmaxf(v0, 0.f); v1 = fmaxf(v1, 0.f); }
            o[i] = pk16(v0, v1);
        }
        uint4 s0 = { __builtin_bit_cast(unsigned int, o[0]), __builtin_bit_cast(unsigned int, o[1]),
                     __builtin_bit_cast(unsigned int, o[2]), __builtin_bit_cast(unsigned int, o[3]) };
        uint4 s1 = { __builtin_bit_cast(unsigned int, o[4]), __builtin_bit_cast(unsigned int, o[5]),
                     __builtin_bit_cast(unsigned int, o[6]), __builtin_bit_cast(unsigned int, o[7]) };
        *(uint4*)orow = s0;
        *(uint4*)(orow + 16) = s1;
    }
}

// ============================ Two-stage pooling ============================
__global__ __launch_bounds__(256) void pool_partial(
    const _Float16* __restrict__ h, const int* __restrict__ startg,
    const int* __restrict__ endg, float* __restrict__ sumP, float* __restrict__ maxP)
{
    __shared__ float4 sS[4][64];
    __shared__ float4 sM[4][64];
    int g = blockIdx.x >> 5, part = blockIdx.x & (NPART - 1);
    int lane = threadIdx.x & 63;
    int sub = threadIdx.x >> 6;
    int c0 = lane * 4;
    int s = startg[g], e = endg[g];
    float4 sum = make_float4(0.f, 0.f, 0.f, 0.f);
    float4 mx = make_float4(-INFINITY, -INFINITY, -INFINITY, -INFINITY);
    for (int i = s + part * 4 + sub; i < e; i += NPART * 4) {
        uint2 u = *(const uint2*)&h[(size_t)i * HCDIM + c0];
        h2 a = bch2(u.x), b = bch2(u.y);
        float4 v = make_float4((float)a.x, (float)a.y, (float)b.x, (float)b.y);
        sum.x += v.x; sum.y += v.y; sum.z += v.z; sum.w += v.w;
        mx.x = fmaxf(mx.x, v.x); mx.y = fmaxf(mx.y, v.y);
        mx.z = fmaxf(mx.z, v.z); mx.w = fmaxf(mx.w, v.w);
    }
    sS[sub][lane] = sum; sM[sub][lane] = mx;
    __syncthreads();
    if (sub == 0) {
        #pragma unroll
        for (int j = 1; j < 4; ++j) {
            float4 a = sS[j][lane], b = sM[j][lane];
            sum.x += a.x; sum.y += a.y; sum.z += a.z; sum.w += a.w;
            mx.x = fmaxf(mx.x, b.x); mx.y = fmaxf(mx.y, b.y);
            mx.z = fmaxf(mx.z, b.z); mx.w = fmaxf(mx.w, b.w);
        }
        size_t o = (size_t)blockIdx.x * HCDIM + c0;
        *(float4*)&sumP[o] = sum;
        *(float4*)&maxP[o] = mx;
    }
}

// Stage 2 + logits + softmax fused
__global__ __launch_bounds__(256) void pool_final_logits(
    const float* __restrict__ sumP, const float* __restrict__ maxP,
    const int* __restrict__ startg, const int* __restrict__ endg,
    const float* __restrict__ Wout, const float* __restrict__ bout,
    float* __restrict__ out)
{
    __shared__ float red[256];
    __shared__ float lg[NCLS];
    int g = blockIdx.x, c = threadIdx.x;
    float s = 0.f, m = -INFINITY;
    #pragma unroll 8
    for (int part = 0; part < NPART; ++part) {
        size_t o = (size_t)(g * NPART + part) * HCDIM + c;
        s += sumP[o];
        m = fmaxf(m, maxP[o]);
    }
    int cnt = endg[g] - startg[g];
    float inv = 1.f / fmaxf((float)cnt, 1.f);
    float pv = s * inv + m;

    for (int j = 0; j < NCLS; ++j) {
        red[c] = pv * Wout[c * NCLS + j];
        __syncthreads();
        for (int off = 128; off > 0; off >>= 1) {
            if (c < off) red[c] += red[c + off];
            __syncthreads();
        }
        if (c == 0) lg[j] = red[0] + bout[j];
        __syncthreads();
    }
    if (c == 0) {
        float mx = fmaxf(lg[0], fmaxf(lg[1], lg[2]));
        float e0 = __expf(lg[0] - mx), e1 = __expf(lg[1] - mx), e2 = __expf(lg[2] - mx);
        float invs = 1.f / (e0 + e1 + e2);
        out[g * NCLS + 0] = e0 * invs;
        out[g * NCLS + 1] = e1 * invs;
        out[g * NCLS + 2] = e2 * invs;
    }
}

// ============================ Orchestration ============================
extern "C" void kernel_launch(void* const* d_in, const int* in_sizes, int n_in,
                              void* d_out, int out_size, void* d_ws, size_t ws_size,
                              hipStream_t stream) {
    const float* x     = (const float*)d_in[0];
    const int*   ei    = (const int*)d_in[1];
    const int*   batch = (const int*)d_in[2];
    const float *Wl[3], *bl[3], *Wr[3], *br[3], *att[3], *bias[3];
    for (int li = 0; li < 3; ++li) {
        int b = 3 + li * 6;
        Wl[li]   = (const float*)d_in[b + 0];
        bl[li]   = (const float*)d_in[b + 1];
        Wr[li]   = (const float*)d_in[b + 2];
        br[li]   = (const float*)d_in[b + 3];
        att[li]  = (const float*)d_in[b + 4];
        bias[li] = (const float*)d_in[b + 5];
    }
    const float* Wout = (const float*)d_in[21];
    const float* bout = (const float*)d_in[22];
    float* out = (float*)d_out;

    size_t off = 0;
    char* wsb = (char*)d_ws;
    auto alloc = [&](size_t bytes) -> char* {
        char* ptr = wsb + off;
        off += (bytes + 255) & ~(size_t)255;
        return ptr;
    };
    int* zblk    = (int*)alloc((N_NODES + 2 * NGRAPH) * sizeof(int));
    int* deg     = zblk;
    int* startg  = zblk + N_NODES;
    int* endg    = zblk + N_NODES + NGRAPH;
    int* rowptr  = (int*)alloc((N_NODES + 1) * sizeof(int));
    int* cursor  = (int*)alloc(N_NODES * sizeof(int));
    int* bsums   = (int*)alloc(256 * sizeof(int));
    int* colx    = (int*)alloc((size_t)(N_EDGES + N_NODES + 8) * sizeof(int));
    _Float16* Abuf = (_Float16*)alloc((size_t)MPAD * HCDIM * sizeof(_Float16));
    _Float16* Bt[3];
    for (int li = 0; li < 3; ++li) {
        int K = (li == 0) ? F_INPUT : HCDIM;
        Bt[li] = (_Float16*)alloc((size_t)512 * K * sizeof(_Float16));
    }
    unsigned char* xl8 = (unsigned char*)alloc((size_t)N_NODES * HCDIM);
    _Float16* xrh  = (_Float16*)alloc((size_t)N_NODES * HCDIM * sizeof(_Float16));
    _Float16* hbuf = (_Float16*)alloc((size_t)N_NODES * HCDIM * sizeof(_Float16));
    float* sumP    = (float*)alloc((size_t)NGRAPH * NPART * HCDIM * sizeof(float));
    float* maxP    = (float*)alloc((size_t)NGRAPH * NPART * HCDIM * sizeof(float));

    hipMemsetAsync(zblk, 0, (N_NODES + 2 * NGRAPH) * sizeof(int), stream);

    hist_boundary_kernel<<<HIST_NB + BND_NB, 256, 0, stream>>>(ei, deg, batch, startg, endg);
    block_scan_kernel<<<SCAN_NB, 256, 0, stream>>>(deg, rowptr, bsums);
    add_off_kernel<<<SCAN_NB, 256, 0, stream>>>(rowptr, cursor, bsums);
    fill_kernel<<<(N_EDGES + N_NODES + 8 + 255) / 256, 256, 0, stream>>>(ei, cursor, colx);

    prep_kernel<<<PREP_NB, 256, 0, stream>>>(x, Abuf, Bt[0], Bt[1], Bt[2],
                                             Wl[0], Wr[0], Wl[1], Wr[1], Wl[2], Wr[2]);

    for (int li = 0; li < 3; ++li) {
        int K = (li == 0) ? F_INPUT : HCDIM;
        gemm_mfma<<<(MPAD / 64) * 4, 256, 0, stream>>>(
            Abuf, Bt[li], K, bl[li], br[li], xl8, xrh);
        if (li < 2) {
            gat_edge<<<N_NODES / 4, 256, 0, stream>>>(
                xl8, xrh, att[li], bias[li], rowptr, colx, nullptr, Abuf, 1);
        } else {
            gat_edge<<<N_NODES / 4, 256, 0, stream>>>(
                xl8, xrh, att[li], bias[li], rowptr, colx, hbuf, nullptr, 0);
        }
    }

    pool_partial<<<NGRAPH * NPART, 256, 0, stream>>>(hbuf, startg, endg, sumP, maxP);
    pool_final_logits<<<NGRAPH, 256, 0, stream>>>(sumP, maxP, startg, endg, Wout, bout, out);
}